// Round 8
// baseline (302.198 us; speedup 1.0000x reference)
//
#include <hip/hip_runtime.h>

// ---------------- helpers ----------------
__device__ __forceinline__ unsigned short f2bf(float f) {
    union { float f; unsigned u; } v; v.f = f;
    unsigned u = v.u;
    unsigned r = (u + 0x7fffu + ((u >> 16) & 1u)) >> 16;
    return (unsigned short)r;
}
__device__ __forceinline__ float bfup(int x) {
    union { unsigned u; float f; } v; v.u = ((unsigned)(unsigned short)x) << 16; return v.f;
}

typedef __attribute__((ext_vector_type(8))) short short8;
typedef __attribute__((ext_vector_type(4))) float floatx4;

// dims
#define Bn 4
#define Ln 256
#define Hn 768
#define Tn 16
#define PITCH 288   // bf16 pitch: 144 dwords, 144%32=16 -> 2-way (free) LDS aliasing

// ---------------- K1: fused LayerNorm (blocks 0..1023) + W1 transpose (1024..1407)
__global__ __launch_bounds__(256) void k_pre(const float* __restrict__ x,
                                             const float* __restrict__ g,
                                             const float* __restrict__ be,
                                             float* __restrict__ out,
                                             const float* __restrict__ W1,
                                             unsigned short* __restrict__ w1t) {
    int bid = blockIdx.x, tid = threadIdx.x;
    if (bid < 1024) {
        int row = bid;
        const float* xr = x + (size_t)row * Hn;
        float v0 = xr[tid], v1 = xr[tid + 256], v2 = xr[tid + 512];
        float s = v0 + v1 + v2;
        float q = v0 * v0 + v1 * v1 + v2 * v2;
        __shared__ float sm[4], qm[4];
        for (int o = 32; o > 0; o >>= 1) { s += __shfl_down(s, o); q += __shfl_down(q, o); }
        if ((tid & 63) == 0) { sm[tid >> 6] = s; qm[tid >> 6] = q; }
        __syncthreads();
        float S = sm[0] + sm[1] + sm[2] + sm[3];
        float Q = qm[0] + qm[1] + qm[2] + qm[3];
        float mean = S * (1.f / 768.f);
        float rstd = rsqrtf(Q * (1.f / 768.f) - mean * mean + 1e-5f);
        float* o0 = out + (size_t)row * Hn;
        o0[tid]       = (v0 - mean) * rstd * g[tid]       + be[tid];
        o0[tid + 256] = (v1 - mean) * rstd * g[tid + 256] + be[tid + 256];
        o0[tid + 512] = (v2 - mean) * rstd * g[tid + 512] + be[tid + 512];
    } else {
        __shared__ float tile[32][33];
        int idx = bid - 1024;
        int kt = idx % 24, nt = idx / 24;
        int k0 = kt * 32, n0 = nt * 32;
        int rowoff = (n0 < 256) ? 0 : 768;
        int col0 = n0 & 255;
        int r = tid >> 3, c = (tid & 7) * 4;
        float4 v = *(const float4*)(W1 + (size_t)(rowoff + k0 + r) * 256 + col0 + c);
        tile[r][c] = v.x; tile[r][c + 1] = v.y; tile[r][c + 2] = v.z; tile[r][c + 3] = v.w;
        __syncthreads();
        ushort4 o;
        o.x = f2bf(tile[c][r]); o.y = f2bf(tile[c + 1][r]);
        o.z = f2bf(tile[c + 2][r]); o.w = f2bf(tile[c + 3][r]);
        *(ushort4*)(w1t + (size_t)(n0 + r) * 768 + k0 + c) = o;
    }
}

// ---------------- K2: span means -> xv[64][1568]; also zero nf row ----------
__global__ __launch_bounds__(256) void k_spans(const float* __restrict__ emb,
                                               const int* __restrict__ ast_, const int* __restrict__ aed_,
                                               const int* __restrict__ ost_, const int* __restrict__ oed_,
                                               const int* __restrict__ sid_,
                                               float* __restrict__ xv,
                                               float* __restrict__ nf) {
    int n = blockIdx.x, b = n >> 4, tid = threadIdx.x;
    int ast = ast_[n], aed = aed_[n], ost = ost_[n], oed = oed_[n], sid = sid_[n];
    float ai = 1.f / (float)(aed - ast + 1);
    float oi = 1.f / (float)(oed - ost + 1);
    const float* eb = emb + (size_t)b * Ln * Hn;
    float* xr = xv + (size_t)n * 1568;
    for (int r = tid; r < 1568; r += 256) {
        float v;
        if (r < 768) {
            float s = 0.f;
            for (int l = ast; l <= aed; ++l) s += eb[l * Hn + r];
            v = s * ai;
        } else if (r < 1536) {
            int h = r - 768;
            float s = 0.f;
            for (int l = ost; l <= oed; ++l) s += eb[l * Hn + h];
            v = s * oi;
        } else if (r < 1539) {
            v = (sid - 2 == r - 1536) ? 1.f : 0.f;
        } else {
            v = 0.f;
        }
        xr[r] = v;
    }
    float* nr = nf + (size_t)n * Hn;
    nr[tid] = 0.f; nr[tid + 256] = 0.f; nr[tid + 512] = 0.f;
}

// ---------------- split-K skinny GEMM: C[M x 768] += A[M x Kpad] @ B[Kb x 768]
__global__ __launch_bounds__(256) void k_skinny(const float* __restrict__ A,
                                                const float* __restrict__ B,
                                                const float* __restrict__ bias,
                                                float* __restrict__ C,
                                                int Kpad, int Kb, int Kc) {
    __shared__ float At[32][33], Bt[32][33];
    int tid = threadIdx.x;
    int n0 = blockIdx.x * 32, m0 = blockIdx.y * 32, z = blockIdx.z;
    int kbeg = z * Kc;
    int kend = kbeg + Kc; if (kend > Kpad) kend = Kpad;
    int lr = tid >> 3, lc = (tid & 7) * 4;
    int tm = tid >> 3, tn4 = (tid & 7) * 4;
    float acc0 = 0.f, acc1 = 0.f, acc2 = 0.f, acc3 = 0.f;
    for (int k0 = kbeg; k0 < kend; k0 += 32) {
        float4 av = *(const float4*)(A + (size_t)(m0 + lr) * Kpad + k0 + lc);
        At[lr][lc] = av.x; At[lr][lc + 1] = av.y; At[lr][lc + 2] = av.z; At[lr][lc + 3] = av.w;
        int gk = k0 + lr;
        float4 bv = {0.f, 0.f, 0.f, 0.f};
        if (gk < Kb) bv = *(const float4*)(B + (size_t)gk * 768 + n0 + lc);
        Bt[lr][lc] = bv.x; Bt[lr][lc + 1] = bv.y; Bt[lr][lc + 2] = bv.z; Bt[lr][lc + 3] = bv.w;
        __syncthreads();
#pragma unroll
        for (int k = 0; k < 32; ++k) {
            float a = At[tm][k];
            acc0 = fmaf(a, Bt[k][tn4], acc0);
            acc1 = fmaf(a, Bt[k][tn4 + 1], acc1);
            acc2 = fmaf(a, Bt[k][tn4 + 2], acc2);
            acc3 = fmaf(a, Bt[k][tn4 + 3], acc3);
        }
        __syncthreads();
    }
    if (z == 0) {
        acc0 += bias[n0 + tn4];
        acc1 += bias[n0 + tn4 + 1];
        acc2 += bias[n0 + tn4 + 2];
        acc3 += bias[n0 + tn4 + 3];
    }
    float* dst = C + (size_t)(m0 + tm) * 768 + n0 + tn4;
    atomicAdd(&dst[0], acc0);
    atomicAdd(&dst[1], acc1);
    atomicAdd(&dst[2], acc2);
    atomicAdd(&dst[3], acc3);
}

// ---------------- K4: graph attention + aggregation (LDS-staged) ----------------
__global__ __launch_bounds__(256) void k_graph(const float* __restrict__ nf,
                                               const int* __restrict__ ast_, const int* __restrict__ aed_,
                                               const int* __restrict__ ost_, const int* __restrict__ oed_,
                                               const float* __restrict__ E,
                                               const float* __restrict__ Wat,
                                               const float* __restrict__ bat,
                                               int* __restrict__ hasin, float* __restrict__ hasedge,
                                               float* __restrict__ agg, float* __restrict__ raw) {
    int b = blockIdx.x, tid = threadIdx.x;
    __shared__ float nfs[16][780];
    __shared__ float Es[2][768];
    __shared__ int ast[16], aed[16], ost[16], oed[16];
    __shared__ float red[256];
    __shared__ float nrm[16], p[16], q[16], rr[2];
    __shared__ float ws2[16][16];
    __shared__ float aes[16][2];
    __shared__ unsigned m0b[16], m1b[16];
    const float* nfb = nf + (size_t)b * 16 * Hn;
    for (int e = tid; e < 3072; e += 256) {
        int r = e / 192, c = (e - r * 192) * 4;
        float4 v = *(const float4*)(nfb + r * Hn + c);
        nfs[r][c] = v.x; nfs[r][c + 1] = v.y; nfs[r][c + 2] = v.z; nfs[r][c + 3] = v.w;
    }
    for (int e = tid; e < 1536; e += 256) ((float*)Es)[e] = E[e];
    if (tid < 16) {
        int n = b * 16 + tid;
        ast[tid] = ast_[n]; aed[tid] = aed_[n]; ost[tid] = ost_[n]; oed[tid] = oed_[n];
        m0b[tid] = 0u; m1b[tid] = 0u;
    }
    __syncthreads();
    int t = tid >> 4, lane = tid & 15;
    float ss = 0.f, pp = 0.f, qq = 0.f;
    for (int h = lane; h < 768; h += 16) {
        float v = nfs[t][h];
        ss = fmaf(v, v, ss);
        float lr = v > 0.f ? v : 0.2f * v;
        pp = fmaf(lr, Wat[h], pp);
        qq = fmaf(lr, Wat[768 + h], qq);
    }
    red[tid] = ss; __syncthreads();
    if (tid < 16) { float s = 0.f; for (int k2 = 0; k2 < 16; ++k2) s += red[tid * 16 + k2]; nrm[tid] = sqrtf(s); }
    __syncthreads();
    red[tid] = pp; __syncthreads();
    if (tid < 16) { float s = 0.f; for (int k2 = 0; k2 < 16; ++k2) s += red[tid * 16 + k2]; p[tid] = s; }
    __syncthreads();
    red[tid] = qq; __syncthreads();
    if (tid < 16) { float s = 0.f; for (int k2 = 0; k2 < 16; ++k2) s += red[tid * 16 + k2]; q[tid] = s; }
    __syncthreads();
    float rp = 0.f;
    if (tid < 32) {
        int e = tid >> 4;
        for (int h = lane; h < 768; h += 16) {
            float v = Es[e][h];
            float lr = v > 0.f ? v : 0.2f * v;
            rp = fmaf(lr, Wat[1536 + h], rp);
        }
    }
    red[tid] = rp; __syncthreads();
    if (tid < 2) { float s = 0.f; for (int k2 = 0; k2 < 16; ++k2) s += red[tid * 16 + k2]; rr[tid] = s; }
    __syncthreads();
    {
        int i = tid >> 4, j = tid & 15;
        const float4* ri = (const float4*)nfs[i];
        const float4* rj = (const float4*)nfs[j];
        float dot = 0.f;
#pragma unroll 4
        for (int h4 = 0; h4 < 192; ++h4) {
            float4 a = ri[h4], c = rj[h4];
            dot = fmaf(a.x, c.x, dot); dot = fmaf(a.y, c.y, dot);
            dot = fmaf(a.z, c.z, dot); dot = fmaf(a.w, c.w, dot);
        }
        float sim = dot / (fmaxf(nrm[i], 1e-8f) * fmaxf(nrm[j], 1e-8f));
        bool ok = (sim > 0.f) && (i != j);
        if (ok && ast[i] == ast[j] && aed[i] == aed[j]) atomicOr(&m0b[i], 1u << j);
        if (ok && ost[i] == ost[j] && oed[i] == oed[j]) atomicOr(&m1b[i], 1u << j);
    }
    __syncthreads();
    if (tid < 16) {
        int tt = tid;
        float battn = bat[0];
        float sc[32];
        float mx = -3.4e38f;
        bool hi = false;
#pragma unroll
        for (int s = 0; s < 16; ++s) {
            bool e0 = (m0b[s] >> tt) & 1u;   // emask[t,s,0] = m0[s,t]
            bool e1 = (m1b[s] >> tt) & 1u;
            float base = p[tt] + q[s] + battn;
            float v0 = e0 ? (base + rr[0]) : -1e9f;
            float v1 = e1 ? (base + rr[1]) : -1e9f;
            sc[2 * s] = v0; sc[2 * s + 1] = v1;
            mx = fmaxf(mx, fmaxf(v0, v1));
            hi = hi || e0 || e1;
        }
        float sum = 0.f;
#pragma unroll
        for (int k2 = 0; k2 < 32; ++k2) { float e = expf(sc[k2] - mx); sc[k2] = e; sum += e; }
        float inv = 1.f / sum;
        float ae0 = 0.f, ae1 = 0.f;
#pragma unroll
        for (int s = 0; s < 16; ++s) {
            float w0 = sc[2 * s] * inv, w1 = sc[2 * s + 1] * inv;
            ws2[tt][s] = w0 + w1;
            ae0 += w0; ae1 += w1;
        }
        aes[tt][0] = ae0; aes[tt][1] = ae1;
        hasin[b * 16 + tt] = hi ? 1 : 0;
        red[tid] = hi ? 1.f : 0.f;
    }
    __syncthreads();
    if (tid == 0) {
        float he = 0.f;
        for (int k2 = 0; k2 < 16; ++k2) he = fmaxf(he, red[k2]);
        hasedge[b] = he;
    }
    for (int nn = 0; nn < 16; ++nn) {
        int n = b * 16 + nn;
        float ae0 = aes[nn][0], ae1 = aes[nn][1];
        float* ag = agg + (size_t)n * 1536;
        float* rw = raw + (size_t)n * Hn;
        for (int f = tid; f < 768; f += 256) {
            float s = 0.f;
#pragma unroll
            for (int s16 = 0; s16 < 16; ++s16) s = fmaf(ws2[nn][s16], nfs[s16][f], s);
            ag[f] = s;
            ag[768 + f] = ae0 * Es[0][f] + ae1 * Es[1][f];
            rw[f] = 0.f;
        }
    }
}

// ---------------- K5b: select + scatter-add into emb ----------------
__global__ __launch_bounds__(256) void k_scatter(const float* __restrict__ raw,
                                                 const float* __restrict__ nf,
                                                 const int* __restrict__ hasin, const float* __restrict__ hasedge,
                                                 const int* __restrict__ ast_, const int* __restrict__ ost_,
                                                 float* __restrict__ emb) {
    int n = blockIdx.x, b = n >> 4, tid = threadIdx.x;
    if (hasedge[b] == 0.f) return;
    int center = (ast_[n] + ost_[n]) >> 1;
    float* dst = emb + (size_t)(b * Ln + center) * Hn;
    int hi = hasin[n];
    const float* src = hi ? (raw + (size_t)n * Hn) : (nf + (size_t)n * Hn);
    for (int h = tid; h < 768; h += 256) {
        float v = src[h];
        if (hi) v = fmaxf(v, 0.f);
        atomicAdd(&dst[h], v);
    }
}

// ---------------- K7: MFMA GEMM  abm[1024][512] = bf16(emb) @ w1t^T (inline cvt)
__global__ __launch_bounds__(64) void k_gemm(const float* __restrict__ emb,
                                             const unsigned short* __restrict__ w1t,
                                             float* __restrict__ abm) {
    int wid = blockIdx.x;                 // 512 waves
    int m0 = (wid >> 4) * 32;
    int n0 = (wid & 15) * 32;
    int lane = threadIdx.x;
    int r = lane & 15, g = lane >> 4;
    const float* Af0 = emb + (size_t)(m0 + r) * 768 + g * 8;
    const float* Af1 = emb + (size_t)(m0 + 16 + r) * 768 + g * 8;
    const short8* Bp0 = (const short8*)(w1t + (size_t)(n0 + r) * 768 + g * 8);
    const short8* Bp1 = (const short8*)(w1t + (size_t)(n0 + 16 + r) * 768 + g * 8);
    floatx4 acc00 = {0.f, 0.f, 0.f, 0.f}, acc01 = {0.f, 0.f, 0.f, 0.f};
    floatx4 acc10 = {0.f, 0.f, 0.f, 0.f}, acc11 = {0.f, 0.f, 0.f, 0.f};
#pragma unroll 4
    for (int ks = 0; ks < 768; ks += 32) {
        float4 x0 = *(const float4*)(Af0 + ks);
        float4 x1 = *(const float4*)(Af0 + ks + 4);
        float4 y0 = *(const float4*)(Af1 + ks);
        float4 y1 = *(const float4*)(Af1 + ks + 4);
        short8 a0, a1;
        union { float f; unsigned u; } cv;
#define PK(dst, idx, val) { cv.f = (val); dst[idx] = (short)((cv.u + 0x8000u) >> 16); }
        PK(a0, 0, x0.x) PK(a0, 1, x0.y) PK(a0, 2, x0.z) PK(a0, 3, x0.w)
        PK(a0, 4, x1.x) PK(a0, 5, x1.y) PK(a0, 6, x1.z) PK(a0, 7, x1.w)
        PK(a1, 0, y0.x) PK(a1, 1, y0.y) PK(a1, 2, y0.z) PK(a1, 3, y0.w)
        PK(a1, 4, y1.x) PK(a1, 5, y1.y) PK(a1, 6, y1.z) PK(a1, 7, y1.w)
#undef PK
        short8 b0 = Bp0[ks >> 3];
        short8 b1 = Bp1[ks >> 3];
        acc00 = __builtin_amdgcn_mfma_f32_16x16x32_bf16(a0, b0, acc00, 0, 0, 0);
        acc01 = __builtin_amdgcn_mfma_f32_16x16x32_bf16(a0, b1, acc01, 0, 0, 0);
        acc10 = __builtin_amdgcn_mfma_f32_16x16x32_bf16(a1, b0, acc10, 0, 0, 0);
        acc11 = __builtin_amdgcn_mfma_f32_16x16x32_bf16(a1, b1, acc11, 0, 0, 0);
    }
#pragma unroll
    for (int t = 0; t < 4; ++t) {
        int row = g * 4 + t;
        abm[(size_t)(m0 + row) * 512 + n0 + r]           = acc00[t];
        abm[(size_t)(m0 + row) * 512 + n0 + 16 + r]      = acc01[t];
        abm[(size_t)(m0 + 16 + row) * 512 + n0 + r]      = acc10[t];
        abm[(size_t)(m0 + 16 + row) * 512 + n0 + 16 + r] = acc11[t];
    }
}

// ---------------- K11: fully fused LN-stats + GELU + MFMA-proj ----------------
__global__ __launch_bounds__(256, 4) void k_hidden3(const float* __restrict__ abm,
                                                    const float* __restrict__ bl1,
                                                    const float* __restrict__ masks,
                                                    const float* __restrict__ g1, const float* __restrict__ b1,
                                                    const float* __restrict__ Wc, const float* __restrict__ bc,
                                                    const float* __restrict__ Wc1, const float* __restrict__ bc1,
                                                    float* __restrict__ out) {
    __shared__ unsigned short As[16][PITCH];
    __shared__ unsigned short Bs[16][PITCH];
    __shared__ unsigned short gsh[256], bsh[256];
    __shared__ short8 Wf[8][64];
    __shared__ float Ds[16][16];
    __shared__ float ms[16][16];
    __shared__ float red2[16][16][4];
    __shared__ float sAs[16], qAs[16], sBs[16], qBs[16];
    int tid = threadIdx.x;
    int jt = blockIdx.x, it = blockIdx.y, b = blockIdx.z;
    int rowA = b * 256 + it * 16;
    int rowB = b * 256 + jt * 16;
    // staging: thread (r=tid>>4, sg=tid&15) handles 16 k's for A-row r and B-row r
    {
        int r = tid >> 4, sg = tid & 15;
        const float* Ar = abm + (size_t)(rowA + r) * 512 + sg * 16;
        const float* Br = abm + (size_t)(rowB + r) * 512 + 256 + sg * 16;
        const float* Lr = bl1 + sg * 16;
        float sa = 0.f, qa = 0.f, sb = 0.f, qb = 0.f;
        short8 va0, va1, vb0, vb1;
#pragma unroll
        for (int u = 0; u < 4; ++u) {
            float4 av = *(const float4*)(Ar + u * 4);
            float4 bv = *(const float4*)(Br + u * 4);
            float4 lv = *(const float4*)(Lr + u * 4);
            float aa[4] = {av.x, av.y, av.z, av.w};
            float bb[4] = {bv.x + lv.x, bv.y + lv.y, bv.z + lv.z, bv.w + lv.w};
#pragma unroll
            for (int e = 0; e < 4; ++e) {
                unsigned short ah = f2bf(aa[e]), bh = f2bf(bb[e]);
                float af = bfup(ah), bf2 = bfup(bh);
                sa += af; qa = fmaf(af, af, qa);
                sb += bf2; qb = fmaf(bf2, bf2, qb);
                int pos = u * 4 + e;
                if (pos < 8) { va0[pos] = (short)ah; vb0[pos] = (short)bh; }
                else         { va1[pos - 8] = (short)ah; vb1[pos - 8] = (short)bh; }
            }
        }
        *(short8*)&As[r][sg * 16]     = va0;
        *(short8*)&As[r][sg * 16 + 8] = va1;
        *(short8*)&Bs[r][sg * 16]     = vb0;
        *(short8*)&Bs[r][sg * 16 + 8] = vb1;
        red2[r][sg][0] = sa; red2[r][sg][1] = qa;
        red2[r][sg][2] = sb; red2[r][sg][3] = qb;
    }
    gsh[tid] = f2bf(g1[tid]);
    bsh[tid] = f2bf(b1[tid]);
#pragma unroll
    for (int u = 0; u < 2; ++u) {
        int e = tid + u * 256;
        int s = e >> 6, l = e & 63;
        int qq2 = l >> 4, nn2 = l & 15;
        short8 wv;
#pragma unroll
        for (int t = 0; t < 8; ++t) {
            int k = s * 32 + qq2 * 8 + t;
            float v = (nn2 < 6) ? Wc[k * 6 + nn2] : ((nn2 < 8) ? Wc1[k * 2 + (nn2 - 6)] : 0.f);
            wv[t] = (short)f2bf(v);
        }
        Wf[s][l] = wv;
    }
    {
        int di = tid >> 4, dj = tid & 15;
        ms[di][dj] = masks[((size_t)(b * 256 + it * 16 + di)) * 256 + jt * 16 + dj];
    }
    __syncthreads();
    // wave 0: D tile via 8 MFMAs from staged bf16; wave 1: reduce stats
    if (tid < 64) {
        int m = tid & 15, q = tid >> 4;
        floatx4 acc = {0.f, 0.f, 0.f, 0.f};
#pragma unroll
        for (int s = 0; s < 8; ++s) {
            short8 a8 = *(const short8*)&As[m][s * 32 + q * 8];
            short8 b8 = *(const short8*)&Bs[m][s * 32 + q * 8];
            acc = __builtin_amdgcn_mfma_f32_16x16x32_bf16(a8, b8, acc, 0, 0, 0);
        }
#pragma unroll
        for (int rg = 0; rg < 4; ++rg) Ds[q * 4 + rg][m] = acc[rg];
    } else if (tid < 128) {
        int t2 = tid - 64;
        int which = t2 >> 4, r = t2 & 15;
        float s = 0.f;
#pragma unroll
        for (int k2 = 0; k2 < 16; ++k2) s += red2[r][k2][which];
        if (which == 0) sAs[r] = s;
        else if (which == 1) qAs[r] = s;
        else if (which == 2) sBs[r] = s;
        else qBs[r] = s;
    }
    __syncthreads();

    int lane = tid & 63, w = tid >> 6;
    int m = lane & 15, q = lane >> 4;
    int iA = w * 4 + (m & 3);
    int n = m;
    float bcs_l = (n < 6) ? bc[n] : ((n < 8) ? bc1[n - 6] : 0.f);
    const float inv256 = 1.f / 256.f;
    const float K1 = -1.5957691216f, K2 = -0.0713548163f;

    for (int p = 0; p < 4; ++p) {
        int jB = p * 4 + (m >> 2);
        float mu = (sAs[iA] + sBs[jB]) * inv256;
        float E2 = (qAs[iA] + 2.f * Ds[iA][jB] + qBs[jB]) * inv256;
        float r_ = rsqrtf(E2 - mu * mu + 1e-5f);
        float c_ = -mu * r_;
        floatx4 acc = {0.f, 0.f, 0.f, 0.f};
#pragma unroll
        for (int s = 0; s < 8; ++s) {
            int ko = s * 32 + q * 8;
            short8 a8 = *(const short8*)&As[iA][ko];
            short8 b8 = *(const short8*)&Bs[jB][ko];
            short8 g8 = *(const short8*)&gsh[ko];
            short8 v8 = *(const short8*)&bsh[ko];
            short8 yv;
#pragma unroll
            for (int t = 0; t < 8; ++t) {
                float h = bfup(a8[t]) + bfup(b8[t]);
                float x = fmaf(h, r_, c_);
                x = fmaf(x, bfup(g8[t]), bfup(v8[t]));
                float mm = fmaf(x * x, K2, K1);
                float e = __expf(x * mm);
                float y = x * __builtin_amdgcn_rcpf(1.f + e);
                union { float f; unsigned u; } cv; cv.f = y;
                yv[t] = (short)((cv.u + 0x8000u) >> 16);
            }
            acc = __builtin_amdgcn_mfma_f32_16x16x32_bf16(yv, Wf[s][lane], acc, 0, 0, 0);
        }
        if (n < 8) {
#pragma unroll
            for (int rg = 0; rg < 4; ++rg) {
                int mp = q * 4 + rg;
                int il = w * 4 + (mp & 3);
                int jl = p * 4 + (mp >> 2);
                float mk = ms[il][jl];
                size_t idx = (((size_t)(b * 256 + it * 16 + il)) * 256 + jt * 16 + jl) * 8 + n;
                out[idx] = (acc[rg] + bcs_l) * mk;
            }
        }
    }
}

// ---------------- launch ----------------
extern "C" void kernel_launch(void* const* d_in, const int* in_sizes, int n_in,
                              void* d_out, int out_size, void* d_ws, size_t ws_size,
                              hipStream_t stream) {
    (void)in_sizes; (void)n_in; (void)out_size; (void)ws_size;
    const float* emb_in = (const float*)d_in[0];
    const float* masks  = (const float*)d_in[1];
    const int* ast = (const int*)d_in[2];
    const int* aed = (const int*)d_in[3];
    const int* ost = (const int*)d_in[4];
    const int* oed = (const int*)d_in[5];
    const int* sid = (const int*)d_in[6];
    const float* E    = (const float*)d_in[7];
    const float* Wtp  = (const float*)d_in[8];
    const float* btp  = (const float*)d_in[9];
    const float* Wat  = (const float*)d_in[10];
    const float* bat  = (const float*)d_in[11];
    const float* Wg   = (const float*)d_in[12];
    const float* bg   = (const float*)d_in[13];
    const float* g0   = (const float*)d_in[14];
    const float* b0   = (const float*)d_in[15];
    const float* W1   = (const float*)d_in[16];
    const float* bl1  = (const float*)d_in[17];
    const float* g1   = (const float*)d_in[18];
    const float* b1   = (const float*)d_in[19];
    const float* Wc   = (const float*)d_in[20];
    const float* bc   = (const float*)d_in[21];
    const float* Wc1  = (const float*)d_in[22];
    const float* bc1  = (const float*)d_in[23];
    float* outp = (float*)d_out;

    float* fw = (float*)d_ws;
    float* emb = fw;                                   // 786432
    float* nf  = fw + 786432;                          // 49152 -> 835584
    int*   hasin = (int*)(fw + 835584);                // 64
    float* hasedge = fw + 835648;                      // 4 (pad to 835712)
    float* xv  = fw + 835712;                          // 100352 -> 936064
    float* agg = fw + 936064;                          // 98304  -> 1034368
    float* raw = fw + 1034368;                         // 49152  -> 1083520
    float* abm = fw + 1083520;                         // 524288 -> 1607808
    unsigned short* w1t = (unsigned short*)(fw + 1607808); // 196608 fl -> 1804416

    k_pre<<<1408, 256, 0, stream>>>(emb_in, g0, b0, emb, W1, w1t);
    k_spans<<<64, 256, 0, stream>>>(emb, ast, aed, ost, oed, sid, xv, nf);
    dim3 gs1(24, 2, 7);
    k_skinny<<<gs1, 256, 0, stream>>>(xv, Wtp, btp, nf, 1568, 1539, 224);
    k_graph<<<4, 256, 0, stream>>>(nf, ast, aed, ost, oed, E, Wat, bat, hasin, hasedge, agg, raw);
    k_skinny<<<gs1, 256, 0, stream>>>(agg, Wg, bg, raw, 1536, 1536, 224);
    k_scatter<<<64, 256, 0, stream>>>(raw, nf, hasin, hasedge, ast, ost, emb);
    k_gemm<<<512, 64, 0, stream>>>(emb, w1t, abm);
    dim3 g6(16, 16, 4);
    k_hidden3<<<g6, 256, 0, stream>>>(abm, bl1, masks, g1, b1, Wc, bc, Wc1, bc1, outp);
}

// Round 9
// 243.534 us; speedup vs baseline: 1.2409x; 1.2409x over previous
//
#include <hip/hip_runtime.h>

// ---------------- helpers ----------------
__device__ __forceinline__ unsigned short f2bf(float f) {
    union { float f; unsigned u; } v; v.f = f;
    unsigned u = v.u;
    unsigned r = (u + 0x7fffu + ((u >> 16) & 1u)) >> 16;
    return (unsigned short)r;
}
__device__ __forceinline__ float bfup(int x) {
    union { unsigned u; float f; } v; v.u = ((unsigned)(unsigned short)x) << 16; return v.f;
}

typedef __attribute__((ext_vector_type(8))) short short8;
typedef __attribute__((ext_vector_type(4))) float floatx4;

// dims
#define Bn 4
#define Ln 256
#define Hn 768
#define Tn 16
#define PITCH 288   // bf16 pitch: 144 dwords, 144%32=16 -> 2-way (free) LDS aliasing

// ---------------- K1: fused LayerNorm (blocks 0..1023) + W1 transpose (1024..1407)
__global__ __launch_bounds__(256) void k_pre(const float* __restrict__ x,
                                             const float* __restrict__ g,
                                             const float* __restrict__ be,
                                             float* __restrict__ out,
                                             const float* __restrict__ W1,
                                             unsigned short* __restrict__ w1t) {
    int bid = blockIdx.x, tid = threadIdx.x;
    if (bid < 1024) {
        int row = bid;
        const float* xr = x + (size_t)row * Hn;
        float v0 = xr[tid], v1 = xr[tid + 256], v2 = xr[tid + 512];
        float s = v0 + v1 + v2;
        float q = v0 * v0 + v1 * v1 + v2 * v2;
        __shared__ float sm[4], qm[4];
        for (int o = 32; o > 0; o >>= 1) { s += __shfl_down(s, o); q += __shfl_down(q, o); }
        if ((tid & 63) == 0) { sm[tid >> 6] = s; qm[tid >> 6] = q; }
        __syncthreads();
        float S = sm[0] + sm[1] + sm[2] + sm[3];
        float Q = qm[0] + qm[1] + qm[2] + qm[3];
        float mean = S * (1.f / 768.f);
        float rstd = rsqrtf(Q * (1.f / 768.f) - mean * mean + 1e-5f);
        float* o0 = out + (size_t)row * Hn;
        o0[tid]       = (v0 - mean) * rstd * g[tid]       + be[tid];
        o0[tid + 256] = (v1 - mean) * rstd * g[tid + 256] + be[tid + 256];
        o0[tid + 512] = (v2 - mean) * rstd * g[tid + 512] + be[tid + 512];
    } else {
        __shared__ float tile[32][33];
        int idx = bid - 1024;
        int kt = idx % 24, nt = idx / 24;
        int k0 = kt * 32, n0 = nt * 32;
        int rowoff = (n0 < 256) ? 0 : 768;
        int col0 = n0 & 255;
        int r = tid >> 3, c = (tid & 7) * 4;
        float4 v = *(const float4*)(W1 + (size_t)(rowoff + k0 + r) * 256 + col0 + c);
        tile[r][c] = v.x; tile[r][c + 1] = v.y; tile[r][c + 2] = v.z; tile[r][c + 3] = v.w;
        __syncthreads();
        ushort4 o;
        o.x = f2bf(tile[c][r]); o.y = f2bf(tile[c + 1][r]);
        o.z = f2bf(tile[c + 2][r]); o.w = f2bf(tile[c + 3][r]);
        *(ushort4*)(w1t + (size_t)(n0 + r) * 768 + k0 + c) = o;
    }
}

// ---------------- K1b: build Wf table + bf16 gamma/beta once (1 block) ----------
// wfg layout: [0..4095] Wf as short8[8][64]; [4096..4351] gsh; [4352..4607] bsh
__global__ __launch_bounds__(256) void k_wf(const float* __restrict__ Wc,
                                            const float* __restrict__ Wc1,
                                            const float* __restrict__ g1,
                                            const float* __restrict__ b1,
                                            unsigned short* __restrict__ wfg) {
    int tid = threadIdx.x;
#pragma unroll
    for (int u = 0; u < 2; ++u) {
        int e = tid + u * 256;
        int s = e >> 6, l = e & 63;
        int qq2 = l >> 4, nn2 = l & 15;
        short8 wv;
#pragma unroll
        for (int t = 0; t < 8; ++t) {
            int k = s * 32 + qq2 * 8 + t;
            float v = (nn2 < 6) ? Wc[k * 6 + nn2] : ((nn2 < 8) ? Wc1[k * 2 + (nn2 - 6)] : 0.f);
            wv[t] = (short)f2bf(v);
        }
        *(short8*)(wfg + e * 8) = wv;
    }
    wfg[4096 + tid] = f2bf(g1[tid]);
    wfg[4352 + tid] = f2bf(b1[tid]);
}

// ---------------- K2: span means -> xv[64][1568]; also zero nf row ----------
__global__ __launch_bounds__(256) void k_spans(const float* __restrict__ emb,
                                               const int* __restrict__ ast_, const int* __restrict__ aed_,
                                               const int* __restrict__ ost_, const int* __restrict__ oed_,
                                               const int* __restrict__ sid_,
                                               float* __restrict__ xv,
                                               float* __restrict__ nf) {
    int n = blockIdx.x, b = n >> 4, tid = threadIdx.x;
    int ast = ast_[n], aed = aed_[n], ost = ost_[n], oed = oed_[n], sid = sid_[n];
    float ai = 1.f / (float)(aed - ast + 1);
    float oi = 1.f / (float)(oed - ost + 1);
    const float* eb = emb + (size_t)b * Ln * Hn;
    float* xr = xv + (size_t)n * 1568;
    for (int r = tid; r < 1568; r += 256) {
        float v;
        if (r < 768) {
            float s = 0.f;
            for (int l = ast; l <= aed; ++l) s += eb[l * Hn + r];
            v = s * ai;
        } else if (r < 1536) {
            int h = r - 768;
            float s = 0.f;
            for (int l = ost; l <= oed; ++l) s += eb[l * Hn + h];
            v = s * oi;
        } else if (r < 1539) {
            v = (sid - 2 == r - 1536) ? 1.f : 0.f;
        } else {
            v = 0.f;
        }
        xr[r] = v;
    }
    float* nr = nf + (size_t)n * Hn;
    nr[tid] = 0.f; nr[tid + 256] = 0.f; nr[tid + 512] = 0.f;
}

// ---------------- split-K skinny GEMM: C[M x 768] += A[M x Kpad] @ B[Kb x 768]
__global__ __launch_bounds__(256) void k_skinny(const float* __restrict__ A,
                                                const float* __restrict__ B,
                                                const float* __restrict__ bias,
                                                float* __restrict__ C,
                                                int Kpad, int Kb, int Kc) {
    __shared__ float At[32][33], Bt[32][33];
    int tid = threadIdx.x;
    int n0 = blockIdx.x * 32, m0 = blockIdx.y * 32, z = blockIdx.z;
    int kbeg = z * Kc;
    int kend = kbeg + Kc; if (kend > Kpad) kend = Kpad;
    int lr = tid >> 3, lc = (tid & 7) * 4;
    int tm = tid >> 3, tn4 = (tid & 7) * 4;
    float acc0 = 0.f, acc1 = 0.f, acc2 = 0.f, acc3 = 0.f;
    for (int k0 = kbeg; k0 < kend; k0 += 32) {
        float4 av = *(const float4*)(A + (size_t)(m0 + lr) * Kpad + k0 + lc);
        At[lr][lc] = av.x; At[lr][lc + 1] = av.y; At[lr][lc + 2] = av.z; At[lr][lc + 3] = av.w;
        int gk = k0 + lr;
        float4 bv = {0.f, 0.f, 0.f, 0.f};
        if (gk < Kb) bv = *(const float4*)(B + (size_t)gk * 768 + n0 + lc);
        Bt[lr][lc] = bv.x; Bt[lr][lc + 1] = bv.y; Bt[lr][lc + 2] = bv.z; Bt[lr][lc + 3] = bv.w;
        __syncthreads();
#pragma unroll
        for (int k = 0; k < 32; ++k) {
            float a = At[tm][k];
            acc0 = fmaf(a, Bt[k][tn4], acc0);
            acc1 = fmaf(a, Bt[k][tn4 + 1], acc1);
            acc2 = fmaf(a, Bt[k][tn4 + 2], acc2);
            acc3 = fmaf(a, Bt[k][tn4 + 3], acc3);
        }
        __syncthreads();
    }
    if (z == 0) {
        acc0 += bias[n0 + tn4];
        acc1 += bias[n0 + tn4 + 1];
        acc2 += bias[n0 + tn4 + 2];
        acc3 += bias[n0 + tn4 + 3];
    }
    float* dst = C + (size_t)(m0 + tm) * 768 + n0 + tn4;
    atomicAdd(&dst[0], acc0);
    atomicAdd(&dst[1], acc1);
    atomicAdd(&dst[2], acc2);
    atomicAdd(&dst[3], acc3);
}

// ---------------- K4: graph attention + aggregation (LDS-staged) ----------------
__global__ __launch_bounds__(256) void k_graph(const float* __restrict__ nf,
                                               const int* __restrict__ ast_, const int* __restrict__ aed_,
                                               const int* __restrict__ ost_, const int* __restrict__ oed_,
                                               const float* __restrict__ E,
                                               const float* __restrict__ Wat,
                                               const float* __restrict__ bat,
                                               int* __restrict__ hasin, float* __restrict__ hasedge,
                                               float* __restrict__ agg, float* __restrict__ raw) {
    int b = blockIdx.x, tid = threadIdx.x;
    __shared__ float nfs[16][780];
    __shared__ float Es[2][768];
    __shared__ int ast[16], aed[16], ost[16], oed[16];
    __shared__ float red[256];
    __shared__ float nrm[16], p[16], q[16], rr[2];
    __shared__ float ws2[16][16];
    __shared__ float aes[16][2];
    __shared__ unsigned m0b[16], m1b[16];
    const float* nfb = nf + (size_t)b * 16 * Hn;
    for (int e = tid; e < 3072; e += 256) {
        int r = e / 192, c = (e - r * 192) * 4;
        float4 v = *(const float4*)(nfb + r * Hn + c);
        nfs[r][c] = v.x; nfs[r][c + 1] = v.y; nfs[r][c + 2] = v.z; nfs[r][c + 3] = v.w;
    }
    for (int e = tid; e < 1536; e += 256) ((float*)Es)[e] = E[e];
    if (tid < 16) {
        int n = b * 16 + tid;
        ast[tid] = ast_[n]; aed[tid] = aed_[n]; ost[tid] = ost_[n]; oed[tid] = oed_[n];
        m0b[tid] = 0u; m1b[tid] = 0u;
    }
    __syncthreads();
    int t = tid >> 4, lane = tid & 15;
    float ss = 0.f, pp = 0.f, qq = 0.f;
    for (int h = lane; h < 768; h += 16) {
        float v = nfs[t][h];
        ss = fmaf(v, v, ss);
        float lr = v > 0.f ? v : 0.2f * v;
        pp = fmaf(lr, Wat[h], pp);
        qq = fmaf(lr, Wat[768 + h], qq);
    }
    red[tid] = ss; __syncthreads();
    if (tid < 16) { float s = 0.f; for (int k2 = 0; k2 < 16; ++k2) s += red[tid * 16 + k2]; nrm[tid] = sqrtf(s); }
    __syncthreads();
    red[tid] = pp; __syncthreads();
    if (tid < 16) { float s = 0.f; for (int k2 = 0; k2 < 16; ++k2) s += red[tid * 16 + k2]; p[tid] = s; }
    __syncthreads();
    red[tid] = qq; __syncthreads();
    if (tid < 16) { float s = 0.f; for (int k2 = 0; k2 < 16; ++k2) s += red[tid * 16 + k2]; q[tid] = s; }
    __syncthreads();
    float rp = 0.f;
    if (tid < 32) {
        int e = tid >> 4;
        for (int h = lane; h < 768; h += 16) {
            float v = Es[e][h];
            float lr = v > 0.f ? v : 0.2f * v;
            rp = fmaf(lr, Wat[1536 + h], rp);
        }
    }
    red[tid] = rp; __syncthreads();
    if (tid < 2) { float s = 0.f; for (int k2 = 0; k2 < 16; ++k2) s += red[tid * 16 + k2]; rr[tid] = s; }
    __syncthreads();
    {
        int i = tid >> 4, j = tid & 15;
        const float4* ri = (const float4*)nfs[i];
        const float4* rj = (const float4*)nfs[j];
        float dot = 0.f;
#pragma unroll 4
        for (int h4 = 0; h4 < 192; ++h4) {
            float4 a = ri[h4], c = rj[h4];
            dot = fmaf(a.x, c.x, dot); dot = fmaf(a.y, c.y, dot);
            dot = fmaf(a.z, c.z, dot); dot = fmaf(a.w, c.w, dot);
        }
        float sim = dot / (fmaxf(nrm[i], 1e-8f) * fmaxf(nrm[j], 1e-8f));
        bool ok = (sim > 0.f) && (i != j);
        if (ok && ast[i] == ast[j] && aed[i] == aed[j]) atomicOr(&m0b[i], 1u << j);
        if (ok && ost[i] == ost[j] && oed[i] == oed[j]) atomicOr(&m1b[i], 1u << j);
    }
    __syncthreads();
    if (tid < 16) {
        int tt = tid;
        float battn = bat[0];
        float sc[32];
        float mx = -3.4e38f;
        bool hi = false;
#pragma unroll
        for (int s = 0; s < 16; ++s) {
            bool e0 = (m0b[s] >> tt) & 1u;   // emask[t,s,0] = m0[s,t]
            bool e1 = (m1b[s] >> tt) & 1u;
            float base = p[tt] + q[s] + battn;
            float v0 = e0 ? (base + rr[0]) : -1e9f;
            float v1 = e1 ? (base + rr[1]) : -1e9f;
            sc[2 * s] = v0; sc[2 * s + 1] = v1;
            mx = fmaxf(mx, fmaxf(v0, v1));
            hi = hi || e0 || e1;
        }
        float sum = 0.f;
#pragma unroll
        for (int k2 = 0; k2 < 32; ++k2) { float e = expf(sc[k2] - mx); sc[k2] = e; sum += e; }
        float inv = 1.f / sum;
        float ae0 = 0.f, ae1 = 0.f;
#pragma unroll
        for (int s = 0; s < 16; ++s) {
            float w0 = sc[2 * s] * inv, w1 = sc[2 * s + 1] * inv;
            ws2[tt][s] = w0 + w1;
            ae0 += w0; ae1 += w1;
        }
        aes[tt][0] = ae0; aes[tt][1] = ae1;
        hasin[b * 16 + tt] = hi ? 1 : 0;
        red[tid] = hi ? 1.f : 0.f;
    }
    __syncthreads();
    if (tid == 0) {
        float he = 0.f;
        for (int k2 = 0; k2 < 16; ++k2) he = fmaxf(he, red[k2]);
        hasedge[b] = he;
    }
    for (int nn = 0; nn < 16; ++nn) {
        int n = b * 16 + nn;
        float ae0 = aes[nn][0], ae1 = aes[nn][1];
        float* ag = agg + (size_t)n * 1536;
        float* rw = raw + (size_t)n * Hn;
        for (int f = tid; f < 768; f += 256) {
            float s = 0.f;
#pragma unroll
            for (int s16 = 0; s16 < 16; ++s16) s = fmaf(ws2[nn][s16], nfs[s16][f], s);
            ag[f] = s;
            ag[768 + f] = ae0 * Es[0][f] + ae1 * Es[1][f];
            rw[f] = 0.f;
        }
    }
}

// ---------------- K5b: select + scatter-add into emb ----------------
__global__ __launch_bounds__(256) void k_scatter(const float* __restrict__ raw,
                                                 const float* __restrict__ nf,
                                                 const int* __restrict__ hasin, const float* __restrict__ hasedge,
                                                 const int* __restrict__ ast_, const int* __restrict__ ost_,
                                                 float* __restrict__ emb) {
    int n = blockIdx.x, b = n >> 4, tid = threadIdx.x;
    if (hasedge[b] == 0.f) return;
    int center = (ast_[n] + ost_[n]) >> 1;
    float* dst = emb + (size_t)(b * Ln + center) * Hn;
    int hi = hasin[n];
    const float* src = hi ? (raw + (size_t)n * Hn) : (nf + (size_t)n * Hn);
    for (int h = tid; h < 768; h += 256) {
        float v = src[h];
        if (hi) v = fmaxf(v, 0.f);
        atomicAdd(&dst[h], v);
    }
}

// ---------------- K7: MFMA GEMM  abm[1024][512] = bf16(emb) @ w1t^T (inline cvt)
__global__ __launch_bounds__(64) void k_gemm(const float* __restrict__ emb,
                                             const unsigned short* __restrict__ w1t,
                                             float* __restrict__ abm) {
    int wid = blockIdx.x;                 // 512 waves
    int m0 = (wid >> 4) * 32;
    int n0 = (wid & 15) * 32;
    int lane = threadIdx.x;
    int r = lane & 15, g = lane >> 4;
    const float* Af0 = emb + (size_t)(m0 + r) * 768 + g * 8;
    const float* Af1 = emb + (size_t)(m0 + 16 + r) * 768 + g * 8;
    const short8* Bp0 = (const short8*)(w1t + (size_t)(n0 + r) * 768 + g * 8);
    const short8* Bp1 = (const short8*)(w1t + (size_t)(n0 + 16 + r) * 768 + g * 8);
    floatx4 acc00 = {0.f, 0.f, 0.f, 0.f}, acc01 = {0.f, 0.f, 0.f, 0.f};
    floatx4 acc10 = {0.f, 0.f, 0.f, 0.f}, acc11 = {0.f, 0.f, 0.f, 0.f};
#pragma unroll 4
    for (int ks = 0; ks < 768; ks += 32) {
        float4 x0 = *(const float4*)(Af0 + ks);
        float4 x1 = *(const float4*)(Af0 + ks + 4);
        float4 y0 = *(const float4*)(Af1 + ks);
        float4 y1 = *(const float4*)(Af1 + ks + 4);
        short8 a0, a1;
        union { float f; unsigned u; } cv;
#define PK(dst, idx, val) { cv.f = (val); dst[idx] = (short)((cv.u + 0x8000u) >> 16); }
        PK(a0, 0, x0.x) PK(a0, 1, x0.y) PK(a0, 2, x0.z) PK(a0, 3, x0.w)
        PK(a0, 4, x1.x) PK(a0, 5, x1.y) PK(a0, 6, x1.z) PK(a0, 7, x1.w)
        PK(a1, 0, y0.x) PK(a1, 1, y0.y) PK(a1, 2, y0.z) PK(a1, 3, y0.w)
        PK(a1, 4, y1.x) PK(a1, 5, y1.y) PK(a1, 6, y1.z) PK(a1, 7, y1.w)
#undef PK
        short8 b0 = Bp0[ks >> 3];
        short8 b1 = Bp1[ks >> 3];
        acc00 = __builtin_amdgcn_mfma_f32_16x16x32_bf16(a0, b0, acc00, 0, 0, 0);
        acc01 = __builtin_amdgcn_mfma_f32_16x16x32_bf16(a0, b1, acc01, 0, 0, 0);
        acc10 = __builtin_amdgcn_mfma_f32_16x16x32_bf16(a1, b0, acc10, 0, 0, 0);
        acc11 = __builtin_amdgcn_mfma_f32_16x16x32_bf16(a1, b1, acc11, 0, 0, 0);
    }
#pragma unroll
    for (int t = 0; t < 4; ++t) {
        int row = g * 4 + t;
        abm[(size_t)(m0 + row) * 512 + n0 + r]           = acc00[t];
        abm[(size_t)(m0 + row) * 512 + n0 + 16 + r]      = acc01[t];
        abm[(size_t)(m0 + 16 + row) * 512 + n0 + r]      = acc10[t];
        abm[(size_t)(m0 + 16 + row) * 512 + n0 + 16 + r] = acc11[t];
    }
}

// ---------------- K11: fully fused LN-stats + GELU + MFMA-proj ----------------
__global__ __launch_bounds__(256) void k_hidden3(const float* __restrict__ abm,
                                                 const float* __restrict__ bl1,
                                                 const float* __restrict__ masks,
                                                 const unsigned short* __restrict__ wfg,
                                                 const float* __restrict__ bc,
                                                 const float* __restrict__ bc1,
                                                 float* __restrict__ out) {
    __shared__ unsigned short As[16][PITCH];
    __shared__ unsigned short Bs[16][PITCH];
    __shared__ unsigned short gsh[256], bsh[256];
    __shared__ short8 Wf[8][64];
    __shared__ float Ds[16][16];
    __shared__ float ms[16][16];
    __shared__ float red2[16][16][4];
    __shared__ float sAs[16], qAs[16], sBs[16], qBs[16];
    int tid = threadIdx.x;
    int jt = blockIdx.x, it = blockIdx.y, b = blockIdx.z;
    int rowA = b * 256 + it * 16;
    int rowB = b * 256 + jt * 16;
    // staging: thread (r=tid>>4, sg=tid&15) handles 16 k's for A-row r and B-row r
    {
        int r = tid >> 4, sg = tid & 15;
        const float* Ar = abm + (size_t)(rowA + r) * 512 + sg * 16;
        const float* Br = abm + (size_t)(rowB + r) * 512 + 256 + sg * 16;
        const float* Lr = bl1 + sg * 16;
        float sa = 0.f, qa = 0.f, sb = 0.f, qb = 0.f;
        short8 va0, va1, vb0, vb1;
#pragma unroll
        for (int u = 0; u < 4; ++u) {
            float4 av = *(const float4*)(Ar + u * 4);
            float4 bv = *(const float4*)(Br + u * 4);
            float4 lv = *(const float4*)(Lr + u * 4);
            float aa[4] = {av.x, av.y, av.z, av.w};
            float bb[4] = {bv.x + lv.x, bv.y + lv.y, bv.z + lv.z, bv.w + lv.w};
#pragma unroll
            for (int e = 0; e < 4; ++e) {
                unsigned short ah = f2bf(aa[e]), bh = f2bf(bb[e]);
                float af = bfup(ah), bf2 = bfup(bh);
                sa += af; qa = fmaf(af, af, qa);
                sb += bf2; qb = fmaf(bf2, bf2, qb);
                int pos = u * 4 + e;
                if (pos < 8) { va0[pos] = (short)ah; vb0[pos] = (short)bh; }
                else         { va1[pos - 8] = (short)ah; vb1[pos - 8] = (short)bh; }
            }
        }
        *(short8*)&As[r][sg * 16]     = va0;
        *(short8*)&As[r][sg * 16 + 8] = va1;
        *(short8*)&Bs[r][sg * 16]     = vb0;
        *(short8*)&Bs[r][sg * 16 + 8] = vb1;
        red2[r][sg][0] = sa; red2[r][sg][1] = qa;
        red2[r][sg][2] = sb; red2[r][sg][3] = qb;
    }
    // staged table loads (built once by k_wf)
#pragma unroll
    for (int u = 0; u < 2; ++u) {
        int e = tid + u * 256;
        ((short8*)Wf)[e] = *(const short8*)(wfg + e * 8);
    }
    gsh[tid] = wfg[4096 + tid];
    bsh[tid] = wfg[4352 + tid];
    {
        int di = tid >> 4, dj = tid & 15;
        ms[di][dj] = masks[((size_t)(b * 256 + it * 16 + di)) * 256 + jt * 16 + dj];
    }
    __syncthreads();
    // wave 0: D tile via 8 MFMAs from staged bf16; wave 1: reduce stats
    if (tid < 64) {
        int m = tid & 15, q = tid >> 4;
        floatx4 acc = {0.f, 0.f, 0.f, 0.f};
#pragma unroll
        for (int s = 0; s < 8; ++s) {
            short8 a8 = *(const short8*)&As[m][s * 32 + q * 8];
            short8 b8 = *(const short8*)&Bs[m][s * 32 + q * 8];
            acc = __builtin_amdgcn_mfma_f32_16x16x32_bf16(a8, b8, acc, 0, 0, 0);
        }
#pragma unroll
        for (int rg = 0; rg < 4; ++rg) Ds[q * 4 + rg][m] = acc[rg];
    } else if (tid < 128) {
        int t2 = tid - 64;
        int which = t2 >> 4, r = t2 & 15;
        float s = 0.f;
#pragma unroll
        for (int k2 = 0; k2 < 16; ++k2) s += red2[r][k2][which];
        if (which == 0) sAs[r] = s;
        else if (which == 1) qAs[r] = s;
        else if (which == 2) sBs[r] = s;
        else qBs[r] = s;
    }
    __syncthreads();

    int lane = tid & 63, w = tid >> 6;
    int m = lane & 15, q = lane >> 4;
    int iA = w * 4 + (m & 3);
    int n = m;
    float bcs_l = (n < 6) ? bc[n] : ((n < 8) ? bc1[n - 6] : 0.f);
    const float inv256 = 1.f / 256.f;
    const float K1 = -1.5957691216f, K2 = -0.0713548163f;

    for (int p = 0; p < 4; ++p) {
        int jB = p * 4 + (m >> 2);
        float mu = (sAs[iA] + sBs[jB]) * inv256;
        float E2 = (qAs[iA] + 2.f * Ds[iA][jB] + qBs[jB]) * inv256;
        float r_ = rsqrtf(E2 - mu * mu + 1e-5f);
        float c_ = -mu * r_;
        floatx4 acc = {0.f, 0.f, 0.f, 0.f};
#pragma unroll
        for (int s = 0; s < 8; ++s) {
            int ko = s * 32 + q * 8;
            short8 a8 = *(const short8*)&As[iA][ko];
            short8 b8 = *(const short8*)&Bs[jB][ko];
            short8 g8 = *(const short8*)&gsh[ko];
            short8 v8 = *(const short8*)&bsh[ko];
            short8 yv;
#pragma unroll
            for (int t = 0; t < 8; ++t) {
                float h = bfup(a8[t]) + bfup(b8[t]);
                float x = fmaf(h, r_, c_);
                x = fmaf(x, bfup(g8[t]), bfup(v8[t]));
                float mm = fmaf(x * x, K2, K1);
                float e = __expf(x * mm);
                float y = x * __builtin_amdgcn_rcpf(1.f + e);
                union { float f; unsigned u; } cv; cv.f = y;
                yv[t] = (short)((cv.u + 0x8000u) >> 16);
            }
            acc = __builtin_amdgcn_mfma_f32_16x16x32_bf16(yv, Wf[s][lane], acc, 0, 0, 0);
        }
        if (n < 8) {
#pragma unroll
            for (int rg = 0; rg < 4; ++rg) {
                int mp = q * 4 + rg;
                int il = w * 4 + (mp & 3);
                int jl = p * 4 + (mp >> 2);
                float mk = ms[il][jl];
                size_t idx = (((size_t)(b * 256 + it * 16 + il)) * 256 + jt * 16 + jl) * 8 + n;
                out[idx] = (acc[rg] + bcs_l) * mk;
            }
        }
    }
}

// ---------------- launch ----------------
extern "C" void kernel_launch(void* const* d_in, const int* in_sizes, int n_in,
                              void* d_out, int out_size, void* d_ws, size_t ws_size,
                              hipStream_t stream) {
    (void)in_sizes; (void)n_in; (void)out_size; (void)ws_size;
    const float* emb_in = (const float*)d_in[0];
    const float* masks  = (const float*)d_in[1];
    const int* ast = (const int*)d_in[2];
    const int* aed = (const int*)d_in[3];
    const int* ost = (const int*)d_in[4];
    const int* oed = (const int*)d_in[5];
    const int* sid = (const int*)d_in[6];
    const float* E    = (const float*)d_in[7];
    const float* Wtp  = (const float*)d_in[8];
    const float* btp  = (const float*)d_in[9];
    const float* Wat  = (const float*)d_in[10];
    const float* bat  = (const float*)d_in[11];
    const float* Wg   = (const float*)d_in[12];
    const float* bg   = (const float*)d_in[13];
    const float* g0   = (const float*)d_in[14];
    const float* b0   = (const float*)d_in[15];
    const float* W1   = (const float*)d_in[16];
    const float* bl1  = (const float*)d_in[17];
    const float* g1   = (const float*)d_in[18];
    const float* b1   = (const float*)d_in[19];
    const float* Wc   = (const float*)d_in[20];
    const float* bc   = (const float*)d_in[21];
    const float* Wc1  = (const float*)d_in[22];
    const float* bc1  = (const float*)d_in[23];
    float* outp = (float*)d_out;

    float* fw = (float*)d_ws;
    float* emb = fw;                                   // 786432
    float* nf  = fw + 786432;                          // 49152 -> 835584
    int*   hasin = (int*)(fw + 835584);                // 64
    float* hasedge = fw + 835648;                      // 4 (pad to 835712)
    float* xv  = fw + 835712;                          // 100352 -> 936064
    float* agg = fw + 936064;                          // 98304  -> 1034368
    float* raw = fw + 1034368;                         // 49152  -> 1083520
    float* abm = fw + 1083520;                         // 524288 -> 1607808
    unsigned short* w1t = (unsigned short*)(fw + 1607808); // 393216 us -> fl 1804416
    unsigned short* wfg = (unsigned short*)(fw + 1804416); // 4608 us

    k_wf<<<1, 256, 0, stream>>>(Wc, Wc1, g1, b1, wfg);
    k_pre<<<1408, 256, 0, stream>>>(emb_in, g0, b0, emb, W1, w1t);
    k_spans<<<64, 256, 0, stream>>>(emb, ast, aed, ost, oed, sid, xv, nf);
    dim3 gs1(24, 2, 7);
    k_skinny<<<gs1, 256, 0, stream>>>(xv, Wtp, btp, nf, 1568, 1539, 224);
    k_graph<<<4, 256, 0, stream>>>(nf, ast, aed, ost, oed, E, Wat, bat, hasin, hasedge, agg, raw);
    k_skinny<<<gs1, 256, 0, stream>>>(agg, Wg, bg, raw, 1536, 1536, 224);
    k_scatter<<<64, 256, 0, stream>>>(raw, nf, hasin, hasedge, ast, ost, emb);
    k_gemm<<<512, 64, 0, stream>>>(emb, w1t, abm);
    dim3 g6(16, 16, 4);
    k_hidden3<<<g6, 256, 0, stream>>>(abm, bl1, masks, wfg, bc, bc1, outp);
}

// Round 10
// 237.400 us; speedup vs baseline: 1.2729x; 1.0258x over previous
//
#include <hip/hip_runtime.h>

// ---------------- helpers ----------------
__device__ __forceinline__ unsigned short f2bf(float f) {
    union { float f; unsigned u; } v; v.f = f;
    unsigned u = v.u;
    unsigned r = (u + 0x7fffu + ((u >> 16) & 1u)) >> 16;
    return (unsigned short)r;
}
__device__ __forceinline__ float bfup(int x) {
    union { unsigned u; float f; } v; v.u = ((unsigned)(unsigned short)x) << 16; return v.f;
}

typedef __attribute__((ext_vector_type(8))) short short8;
typedef __attribute__((ext_vector_type(4))) float floatx4;

// dims
#define Bn 4
#define Ln 256
#define Hn 768
#define Tn 16
#define PITCH 288   // bf16 pitch: 144 dwords, 144%32=16 -> 2-way (free) LDS aliasing

// ---------------- K1: LN (0..1023) + W1t (1024..1407) + Wf table (1408) + spans (1409..1472)
__global__ __launch_bounds__(256) void k_pre(const float* __restrict__ x,
                                             const float* __restrict__ g,
                                             const float* __restrict__ be,
                                             float* __restrict__ out,
                                             const float* __restrict__ W1,
                                             unsigned short* __restrict__ w1t,
                                             const float* __restrict__ Wc,
                                             const float* __restrict__ Wc1,
                                             const float* __restrict__ g1,
                                             const float* __restrict__ b1,
                                             unsigned short* __restrict__ wfg,
                                             const int* __restrict__ ast_, const int* __restrict__ aed_,
                                             const int* __restrict__ ost_, const int* __restrict__ oed_,
                                             const int* __restrict__ sid_,
                                             float* __restrict__ xv,
                                             float* __restrict__ nf) {
    int bid = blockIdx.x, tid = threadIdx.x;
    if (bid < 1024) {
        int row = bid;
        const float* xr = x + (size_t)row * Hn;
        float v0 = xr[tid], v1 = xr[tid + 256], v2 = xr[tid + 512];
        float s = v0 + v1 + v2;
        float q = v0 * v0 + v1 * v1 + v2 * v2;
        __shared__ float sm[4], qm[4];
        for (int o = 32; o > 0; o >>= 1) { s += __shfl_down(s, o); q += __shfl_down(q, o); }
        if ((tid & 63) == 0) { sm[tid >> 6] = s; qm[tid >> 6] = q; }
        __syncthreads();
        float S = sm[0] + sm[1] + sm[2] + sm[3];
        float Q = qm[0] + qm[1] + qm[2] + qm[3];
        float mean = S * (1.f / 768.f);
        float rstd = rsqrtf(Q * (1.f / 768.f) - mean * mean + 1e-5f);
        float* o0 = out + (size_t)row * Hn;
        o0[tid]       = (v0 - mean) * rstd * g[tid]       + be[tid];
        o0[tid + 256] = (v1 - mean) * rstd * g[tid + 256] + be[tid + 256];
        o0[tid + 512] = (v2 - mean) * rstd * g[tid + 512] + be[tid + 512];
    } else if (bid < 1408) {
        __shared__ float tile[32][33];
        int idx = bid - 1024;
        int kt = idx % 24, nt = idx / 24;
        int k0 = kt * 32, n0 = nt * 32;
        int rowoff = (n0 < 256) ? 0 : 768;
        int col0 = n0 & 255;
        int r = tid >> 3, c = (tid & 7) * 4;
        float4 v = *(const float4*)(W1 + (size_t)(rowoff + k0 + r) * 256 + col0 + c);
        tile[r][c] = v.x; tile[r][c + 1] = v.y; tile[r][c + 2] = v.z; tile[r][c + 3] = v.w;
        __syncthreads();
        ushort4 o;
        o.x = f2bf(tile[c][r]); o.y = f2bf(tile[c + 1][r]);
        o.z = f2bf(tile[c + 2][r]); o.w = f2bf(tile[c + 3][r]);
        *(ushort4*)(w1t + (size_t)(n0 + r) * 768 + k0 + c) = o;
    } else if (bid == 1408) {
        // Wf table + bf16 gamma/beta
#pragma unroll
        for (int u = 0; u < 2; ++u) {
            int e = tid + u * 256;
            int s = e >> 6, l = e & 63;
            int qq2 = l >> 4, nn2 = l & 15;
            short8 wv;
#pragma unroll
            for (int t = 0; t < 8; ++t) {
                int k = s * 32 + qq2 * 8 + t;
                float v = (nn2 < 6) ? Wc[k * 6 + nn2] : ((nn2 < 8) ? Wc1[k * 2 + (nn2 - 6)] : 0.f);
                wv[t] = (short)f2bf(v);
            }
            *(short8*)(wfg + e * 8) = wv;
        }
        wfg[4096 + tid] = f2bf(g1[tid]);
        wfg[4352 + tid] = f2bf(b1[tid]);
    } else {
        // spans with own LN stats (reads pristine emb_in = x)
        __shared__ float rstdA[3], rstdO[3], cc[2];
        __shared__ float sred[4], qred[4];
        int n = bid - 1409, b = n >> 4;
        int ast = ast_[n], aed = aed_[n], ost = ost_[n], oed = oed_[n], sid = sid_[n];
        int na = aed - ast + 1, no2 = oed - ost + 1;
        if (tid == 0) { cc[0] = 0.f; cc[1] = 0.f; }
        __syncthreads();
        for (int slot = 0; slot < 6; ++slot) {
            int isA = slot < 3;
            int off = isA ? slot : slot - 3;
            int cnt = isA ? na : no2;
            int row = (isA ? ast : ost) + off;
            if (off < cnt) {
                const float* xr = x + (size_t)(b * 256 + row) * Hn;
                float v0 = xr[tid], v1 = xr[tid + 256], v2 = xr[tid + 512];
                float s = v0 + v1 + v2;
                float q = v0 * v0 + v1 * v1 + v2 * v2;
                for (int o = 32; o > 0; o >>= 1) { s += __shfl_down(s, o); q += __shfl_down(q, o); }
                if ((tid & 63) == 0) { sred[tid >> 6] = s; qred[tid >> 6] = q; }
            }
            __syncthreads();
            if (off < cnt && tid == 0) {
                float S = sred[0] + sred[1] + sred[2] + sred[3];
                float Q = qred[0] + qred[1] + qred[2] + qred[3];
                float mean = S * (1.f / 768.f);
                float rstd = rsqrtf(Q * (1.f / 768.f) - mean * mean + 1e-5f);
                if (isA) { rstdA[off] = rstd; cc[0] += mean * rstd; }
                else     { rstdO[off] = rstd; cc[1] += mean * rstd; }
            }
            __syncthreads();
        }
        float ai = 1.f / (float)na, oi = 1.f / (float)no2;
        float cA = cc[0] * ai, cO = cc[1] * oi;
        float* xrr = xv + (size_t)n * 1568;
        const float* eb = x + (size_t)b * Ln * Hn;
        for (int r = tid; r < 1568; r += 256) {
            float v;
            if (r < 768) {
                float sa = 0.f;
                for (int l = 0; l < na; ++l) sa = fmaf(eb[(ast + l) * Hn + r], rstdA[l], sa);
                v = fmaf(g[r], sa * ai - cA, be[r]);
            } else if (r < 1536) {
                int h = r - 768;
                float so = 0.f;
                for (int l = 0; l < no2; ++l) so = fmaf(eb[(ost + l) * Hn + h], rstdO[l], so);
                v = fmaf(g[h], so * oi - cO, be[h]);
            } else if (r < 1539) {
                v = (sid - 2 == r - 1536) ? 1.f : 0.f;
            } else {
                v = 0.f;
            }
            xrr[r] = v;
        }
        float* nr = nf + (size_t)n * Hn;
        nr[tid] = 0.f; nr[tid + 256] = 0.f; nr[tid + 512] = 0.f;
    }
}

// ---------------- split-K skinny GEMM: C[M x 768] += A[M x Kpad] @ B[Kb x 768]
__global__ __launch_bounds__(256) void k_skinny(const float* __restrict__ A,
                                                const float* __restrict__ B,
                                                const float* __restrict__ bias,
                                                float* __restrict__ C,
                                                int Kpad, int Kb, int Kc) {
    __shared__ float At[32][33], Bt[32][33];
    int tid = threadIdx.x;
    int n0 = blockIdx.x * 32, m0 = blockIdx.y * 32, z = blockIdx.z;
    int kbeg = z * Kc;
    int kend = kbeg + Kc; if (kend > Kpad) kend = Kpad;
    int lr = tid >> 3, lc = (tid & 7) * 4;
    int tm = tid >> 3, tn4 = (tid & 7) * 4;
    float acc0 = 0.f, acc1 = 0.f, acc2 = 0.f, acc3 = 0.f;
    for (int k0 = kbeg; k0 < kend; k0 += 32) {
        float4 av = *(const float4*)(A + (size_t)(m0 + lr) * Kpad + k0 + lc);
        At[lr][lc] = av.x; At[lr][lc + 1] = av.y; At[lr][lc + 2] = av.z; At[lr][lc + 3] = av.w;
        int gk = k0 + lr;
        float4 bv = {0.f, 0.f, 0.f, 0.f};
        if (gk < Kb) bv = *(const float4*)(B + (size_t)gk * 768 + n0 + lc);
        Bt[lr][lc] = bv.x; Bt[lr][lc + 1] = bv.y; Bt[lr][lc + 2] = bv.z; Bt[lr][lc + 3] = bv.w;
        __syncthreads();
#pragma unroll
        for (int k = 0; k < 32; ++k) {
            float a = At[tm][k];
            acc0 = fmaf(a, Bt[k][tn4], acc0);
            acc1 = fmaf(a, Bt[k][tn4 + 1], acc1);
            acc2 = fmaf(a, Bt[k][tn4 + 2], acc2);
            acc3 = fmaf(a, Bt[k][tn4 + 3], acc3);
        }
        __syncthreads();
    }
    if (z == 0) {
        acc0 += bias[n0 + tn4];
        acc1 += bias[n0 + tn4 + 1];
        acc2 += bias[n0 + tn4 + 2];
        acc3 += bias[n0 + tn4 + 3];
    }
    float* dst = C + (size_t)(m0 + tm) * 768 + n0 + tn4;
    atomicAdd(&dst[0], acc0);
    atomicAdd(&dst[1], acc1);
    atomicAdd(&dst[2], acc2);
    atomicAdd(&dst[3], acc3);
}

// ---------------- K4: graph attention + aggregation (LDS-staged) ----------------
__global__ __launch_bounds__(256) void k_graph(const float* __restrict__ nf,
                                               const int* __restrict__ ast_, const int* __restrict__ aed_,
                                               const int* __restrict__ ost_, const int* __restrict__ oed_,
                                               const float* __restrict__ E,
                                               const float* __restrict__ Wat,
                                               const float* __restrict__ bat,
                                               int* __restrict__ hasin, float* __restrict__ hasedge,
                                               float* __restrict__ agg, float* __restrict__ raw) {
    int b = blockIdx.x, tid = threadIdx.x;
    __shared__ float nfs[16][780];
    __shared__ float Es[2][768];
    __shared__ int ast[16], aed[16], ost[16], oed[16];
    __shared__ float red[256];
    __shared__ float nrm[16], p[16], q[16], rr[2];
    __shared__ float ws2[16][16];
    __shared__ float aes[16][2];
    __shared__ unsigned m0b[16], m1b[16];
    const float* nfb = nf + (size_t)b * 16 * Hn;
    for (int e = tid; e < 3072; e += 256) {
        int r = e / 192, c = (e - r * 192) * 4;
        float4 v = *(const float4*)(nfb + r * Hn + c);
        nfs[r][c] = v.x; nfs[r][c + 1] = v.y; nfs[r][c + 2] = v.z; nfs[r][c + 3] = v.w;
    }
    for (int e = tid; e < 1536; e += 256) ((float*)Es)[e] = E[e];
    if (tid < 16) {
        int n = b * 16 + tid;
        ast[tid] = ast_[n]; aed[tid] = aed_[n]; ost[tid] = ost_[n]; oed[tid] = oed_[n];
        m0b[tid] = 0u; m1b[tid] = 0u;
    }
    __syncthreads();
    int t = tid >> 4, lane = tid & 15;
    float ss = 0.f, pp = 0.f, qq = 0.f;
    for (int h = lane; h < 768; h += 16) {
        float v = nfs[t][h];
        ss = fmaf(v, v, ss);
        float lr = v > 0.f ? v : 0.2f * v;
        pp = fmaf(lr, Wat[h], pp);
        qq = fmaf(lr, Wat[768 + h], qq);
    }
    red[tid] = ss; __syncthreads();
    if (tid < 16) { float s = 0.f; for (int k2 = 0; k2 < 16; ++k2) s += red[tid * 16 + k2]; nrm[tid] = sqrtf(s); }
    __syncthreads();
    red[tid] = pp; __syncthreads();
    if (tid < 16) { float s = 0.f; for (int k2 = 0; k2 < 16; ++k2) s += red[tid * 16 + k2]; p[tid] = s; }
    __syncthreads();
    red[tid] = qq; __syncthreads();
    if (tid < 16) { float s = 0.f; for (int k2 = 0; k2 < 16; ++k2) s += red[tid * 16 + k2]; q[tid] = s; }
    __syncthreads();
    float rp = 0.f;
    if (tid < 32) {
        int e = tid >> 4;
        for (int h = lane; h < 768; h += 16) {
            float v = Es[e][h];
            float lr = v > 0.f ? v : 0.2f * v;
            rp = fmaf(lr, Wat[1536 + h], rp);
        }
    }
    red[tid] = rp; __syncthreads();
    if (tid < 2) { float s = 0.f; for (int k2 = 0; k2 < 16; ++k2) s += red[tid * 16 + k2]; rr[tid] = s; }
    __syncthreads();
    {
        int i = tid >> 4, j = tid & 15;
        const float4* ri = (const float4*)nfs[i];
        const float4* rj = (const float4*)nfs[j];
        float dot = 0.f;
#pragma unroll 4
        for (int h4 = 0; h4 < 192; ++h4) {
            float4 a = ri[h4], c = rj[h4];
            dot = fmaf(a.x, c.x, dot); dot = fmaf(a.y, c.y, dot);
            dot = fmaf(a.z, c.z, dot); dot = fmaf(a.w, c.w, dot);
        }
        float sim = dot / (fmaxf(nrm[i], 1e-8f) * fmaxf(nrm[j], 1e-8f));
        bool ok = (sim > 0.f) && (i != j);
        if (ok && ast[i] == ast[j] && aed[i] == aed[j]) atomicOr(&m0b[i], 1u << j);
        if (ok && ost[i] == ost[j] && oed[i] == oed[j]) atomicOr(&m1b[i], 1u << j);
    }
    __syncthreads();
    if (tid < 16) {
        int tt = tid;
        float battn = bat[0];
        float sc[32];
        float mx = -3.4e38f;
        bool hi = false;
#pragma unroll
        for (int s = 0; s < 16; ++s) {
            bool e0 = (m0b[s] >> tt) & 1u;   // emask[t,s,0] = m0[s,t]
            bool e1 = (m1b[s] >> tt) & 1u;
            float base = p[tt] + q[s] + battn;
            float v0 = e0 ? (base + rr[0]) : -1e9f;
            float v1 = e1 ? (base + rr[1]) : -1e9f;
            sc[2 * s] = v0; sc[2 * s + 1] = v1;
            mx = fmaxf(mx, fmaxf(v0, v1));
            hi = hi || e0 || e1;
        }
        float sum = 0.f;
#pragma unroll
        for (int k2 = 0; k2 < 32; ++k2) { float e = expf(sc[k2] - mx); sc[k2] = e; sum += e; }
        float inv = 1.f / sum;
        float ae0 = 0.f, ae1 = 0.f;
#pragma unroll
        for (int s = 0; s < 16; ++s) {
            float w0 = sc[2 * s] * inv, w1 = sc[2 * s + 1] * inv;
            ws2[tt][s] = w0 + w1;
            ae0 += w0; ae1 += w1;
        }
        aes[tt][0] = ae0; aes[tt][1] = ae1;
        hasin[b * 16 + tt] = hi ? 1 : 0;
        red[tid] = hi ? 1.f : 0.f;
    }
    __syncthreads();
    if (tid == 0) {
        float he = 0.f;
        for (int k2 = 0; k2 < 16; ++k2) he = fmaxf(he, red[k2]);
        hasedge[b] = he;
    }
    for (int nn = 0; nn < 16; ++nn) {
        int n = b * 16 + nn;
        float ae0 = aes[nn][0], ae1 = aes[nn][1];
        float* ag = agg + (size_t)n * 1536;
        float* rw = raw + (size_t)n * Hn;
        for (int f = tid; f < 768; f += 256) {
            float s = 0.f;
#pragma unroll
            for (int s16 = 0; s16 < 16; ++s16) s = fmaf(ws2[nn][s16], nfs[s16][f], s);
            ag[f] = s;
            ag[768 + f] = ae0 * Es[0][f] + ae1 * Es[1][f];
            rw[f] = 0.f;
        }
    }
}

// ---------------- K5b: select + scatter-add into emb ----------------
__global__ __launch_bounds__(256) void k_scatter(const float* __restrict__ raw,
                                                 const float* __restrict__ nf,
                                                 const int* __restrict__ hasin, const float* __restrict__ hasedge,
                                                 const int* __restrict__ ast_, const int* __restrict__ ost_,
                                                 float* __restrict__ emb) {
    int n = blockIdx.x, b = n >> 4, tid = threadIdx.x;
    if (hasedge[b] == 0.f) return;
    int center = (ast_[n] + ost_[n]) >> 1;
    float* dst = emb + (size_t)(b * Ln + center) * Hn;
    int hi = hasin[n];
    const float* src = hi ? (raw + (size_t)n * Hn) : (nf + (size_t)n * Hn);
    for (int h = tid; h < 768; h += 256) {
        float v = src[h];
        if (hi) v = fmaxf(v, 0.f);
        atomicAdd(&dst[h], v);
    }
}

// ---------------- K7: MFMA GEMM  abm[1024][512] = bf16(emb) @ w1t^T (inline cvt)
__global__ __launch_bounds__(64) void k_gemm(const float* __restrict__ emb,
                                             const unsigned short* __restrict__ w1t,
                                             float* __restrict__ abm) {
    int wid = blockIdx.x;                 // 512 waves
    int m0 = (wid >> 4) * 32;
    int n0 = (wid & 15) * 32;
    int lane = threadIdx.x;
    int r = lane & 15, g = lane >> 4;
    const float* Af0 = emb + (size_t)(m0 + r) * 768 + g * 8;
    const float* Af1 = emb + (size_t)(m0 + 16 + r) * 768 + g * 8;
    const short8* Bp0 = (const short8*)(w1t + (size_t)(n0 + r) * 768 + g * 8);
    const short8* Bp1 = (const short8*)(w1t + (size_t)(n0 + 16 + r) * 768 + g * 8);
    floatx4 acc00 = {0.f, 0.f, 0.f, 0.f}, acc01 = {0.f, 0.f, 0.f, 0.f};
    floatx4 acc10 = {0.f, 0.f, 0.f, 0.f}, acc11 = {0.f, 0.f, 0.f, 0.f};
#pragma unroll 4
    for (int ks = 0; ks < 768; ks += 32) {
        float4 x0 = *(const float4*)(Af0 + ks);
        float4 x1 = *(const float4*)(Af0 + ks + 4);
        float4 y0 = *(const float4*)(Af1 + ks);
        float4 y1 = *(const float4*)(Af1 + ks + 4);
        short8 a0, a1;
        union { float f; unsigned u; } cv;
#define PK(dst, idx, val) { cv.f = (val); dst[idx] = (short)((cv.u + 0x8000u) >> 16); }
        PK(a0, 0, x0.x) PK(a0, 1, x0.y) PK(a0, 2, x0.z) PK(a0, 3, x0.w)
        PK(a0, 4, x1.x) PK(a0, 5, x1.y) PK(a0, 6, x1.z) PK(a0, 7, x1.w)
        PK(a1, 0, y0.x) PK(a1, 1, y0.y) PK(a1, 2, y0.z) PK(a1, 3, y0.w)
        PK(a1, 4, y1.x) PK(a1, 5, y1.y) PK(a1, 6, y1.z) PK(a1, 7, y1.w)
#undef PK
        short8 b0 = Bp0[ks >> 3];
        short8 b1 = Bp1[ks >> 3];
        acc00 = __builtin_amdgcn_mfma_f32_16x16x32_bf16(a0, b0, acc00, 0, 0, 0);
        acc01 = __builtin_amdgcn_mfma_f32_16x16x32_bf16(a0, b1, acc01, 0, 0, 0);
        acc10 = __builtin_amdgcn_mfma_f32_16x16x32_bf16(a1, b0, acc10, 0, 0, 0);
        acc11 = __builtin_amdgcn_mfma_f32_16x16x32_bf16(a1, b1, acc11, 0, 0, 0);
    }
#pragma unroll
    for (int t = 0; t < 4; ++t) {
        int row = g * 4 + t;
        abm[(size_t)(m0 + row) * 512 + n0 + r]           = acc00[t];
        abm[(size_t)(m0 + row) * 512 + n0 + 16 + r]      = acc01[t];
        abm[(size_t)(m0 + 16 + row) * 512 + n0 + r]      = acc10[t];
        abm[(size_t)(m0 + 16 + row) * 512 + n0 + 16 + r] = acc11[t];
    }
}

// ---------------- K11: fully fused LN-stats + GELU + MFMA-proj ----------------
__global__ __launch_bounds__(256) void k_hidden3(const float* __restrict__ abm,
                                                 const float* __restrict__ bl1,
                                                 const float* __restrict__ masks,
                                                 const unsigned short* __restrict__ wfg,
                                                 const float* __restrict__ bc,
                                                 const float* __restrict__ bc1,
                                                 float* __restrict__ out) {
    __shared__ unsigned short As[16][PITCH];
    __shared__ unsigned short Bs[16][PITCH];
    __shared__ unsigned short gsh[256], bsh[256];
    __shared__ short8 Wf[8][64];
    __shared__ float Ds[16][16];
    __shared__ float ms[16][16];
    __shared__ float sAs[16], qAs[16], sBs[16], qBs[16];
    int tid = threadIdx.x;
    int jt = blockIdx.x, it = blockIdx.y, b = blockIdx.z;
    int rowA = b * 256 + it * 16;
    int rowB = b * 256 + jt * 16;
    // staging: thread (r=tid>>4, sg=tid&15) handles 16 k's; stats reduced via shuffles
    {
        int r = tid >> 4, sg = tid & 15;
        const float* Ar = abm + (size_t)(rowA + r) * 512 + sg * 16;
        const float* Br = abm + (size_t)(rowB + r) * 512 + 256 + sg * 16;
        const float* Lr = bl1 + sg * 16;
        float sa = 0.f, qa = 0.f, sb = 0.f, qb = 0.f;
        short8 va0, va1, vb0, vb1;
#pragma unroll
        for (int u = 0; u < 4; ++u) {
            float4 av = *(const float4*)(Ar + u * 4);
            float4 bv = *(const float4*)(Br + u * 4);
            float4 lv = *(const float4*)(Lr + u * 4);
            float aa[4] = {av.x, av.y, av.z, av.w};
            float bb[4] = {bv.x + lv.x, bv.y + lv.y, bv.z + lv.z, bv.w + lv.w};
#pragma unroll
            for (int e = 0; e < 4; ++e) {
                unsigned short ah = f2bf(aa[e]), bh = f2bf(bb[e]);
                float af = bfup(ah), bf2 = bfup(bh);
                sa += af; qa = fmaf(af, af, qa);
                sb += bf2; qb = fmaf(bf2, bf2, qb);
                int pos = u * 4 + e;
                if (pos < 8) { va0[pos] = (short)ah; vb0[pos] = (short)bh; }
                else         { va1[pos - 8] = (short)ah; vb1[pos - 8] = (short)bh; }
            }
        }
        *(short8*)&As[r][sg * 16]     = va0;
        *(short8*)&As[r][sg * 16 + 8] = va1;
        *(short8*)&Bs[r][sg * 16]     = vb0;
        *(short8*)&Bs[r][sg * 16 + 8] = vb1;
        // 16-lane shuffle reduction (groups are contiguous within the wave)
        for (int o = 8; o > 0; o >>= 1) {
            sa += __shfl_down(sa, o); qa += __shfl_down(qa, o);
            sb += __shfl_down(sb, o); qb += __shfl_down(qb, o);
        }
        if (sg == 0) { sAs[r] = sa; qAs[r] = qa; sBs[r] = sb; qBs[r] = qb; }
    }
    // staged table loads (built once by k_pre)
#pragma unroll
    for (int u = 0; u < 2; ++u) {
        int e = tid + u * 256;
        ((short8*)Wf)[e] = *(const short8*)(wfg + e * 8);
    }
    gsh[tid] = wfg[4096 + tid];
    bsh[tid] = wfg[4352 + tid];
    {
        int di = tid >> 4, dj = tid & 15;
        ms[di][dj] = masks[((size_t)(b * 256 + it * 16 + di)) * 256 + jt * 16 + dj];
    }
    __syncthreads();
    // wave 0: D tile via 8 MFMAs from staged bf16
    if (tid < 64) {
        int m = tid & 15, q = tid >> 4;
        floatx4 acc = {0.f, 0.f, 0.f, 0.f};
#pragma unroll
        for (int s = 0; s < 8; ++s) {
            short8 a8 = *(const short8*)&As[m][s * 32 + q * 8];
            short8 b8 = *(const short8*)&Bs[m][s * 32 + q * 8];
            acc = __builtin_amdgcn_mfma_f32_16x16x32_bf16(a8, b8, acc, 0, 0, 0);
        }
#pragma unroll
        for (int rg = 0; rg < 4; ++rg) Ds[q * 4 + rg][m] = acc[rg];
    }
    __syncthreads();

    int lane = tid & 63, w = tid >> 6;
    int m = lane & 15, q = lane >> 4;
    int iA = w * 4 + (m & 3);
    int n = m;
    float bcs_l = (n < 6) ? bc[n] : ((n < 8) ? bc1[n - 6] : 0.f);
    const float inv256 = 1.f / 256.f;
    const float K1 = -1.5957691216f, K2 = -0.0713548163f;

    for (int p = 0; p < 4; ++p) {
        int jB = p * 4 + (m >> 2);
        float mu = (sAs[iA] + sBs[jB]) * inv256;
        float E2 = (qAs[iA] + 2.f * Ds[iA][jB] + qBs[jB]) * inv256;
        float r_ = rsqrtf(E2 - mu * mu + 1e-5f);
        float c_ = -mu * r_;
        floatx4 acc = {0.f, 0.f, 0.f, 0.f};
#pragma unroll
        for (int s = 0; s < 8; ++s) {
            int ko = s * 32 + q * 8;
            short8 a8 = *(const short8*)&As[iA][ko];
            short8 b8 = *(const short8*)&Bs[jB][ko];
            short8 g8 = *(const short8*)&gsh[ko];
            short8 v8 = *(const short8*)&bsh[ko];
            short8 yv;
#pragma unroll
            for (int t = 0; t < 8; ++t) {
                float h = bfup(a8[t]) + bfup(b8[t]);
                float x = fmaf(h, r_, c_);
                x = fmaf(x, bfup(g8[t]), bfup(v8[t]));
                float mm = fmaf(x * x, K2, K1);
                float e = __expf(x * mm);
                float y = x * __builtin_amdgcn_rcpf(1.f + e);
                union { float f; unsigned u; } cv; cv.f = y;
                yv[t] = (short)((cv.u + 0x8000u) >> 16);
            }
            acc = __builtin_amdgcn_mfma_f32_16x16x32_bf16(yv, Wf[s][lane], acc, 0, 0, 0);
        }
        if (n < 8) {
#pragma unroll
            for (int rg = 0; rg < 4; ++rg) {
                int mp = q * 4 + rg;
                int il = w * 4 + (mp & 3);
                int jl = p * 4 + (mp >> 2);
                float mk = ms[il][jl];
                size_t idx = (((size_t)(b * 256 + it * 16 + il)) * 256 + jt * 16 + jl) * 8 + n;
                out[idx] = (acc[rg] + bcs_l) * mk;
            }
        }
    }
}

// ---------------- launch ----------------
extern "C" void kernel_launch(void* const* d_in, const int* in_sizes, int n_in,
                              void* d_out, int out_size, void* d_ws, size_t ws_size,
                              hipStream_t stream) {
    (void)in_sizes; (void)n_in; (void)out_size; (void)ws_size;
    const float* emb_in = (const float*)d_in[0];
    const float* masks  = (const float*)d_in[1];
    const int* ast = (const int*)d_in[2];
    const int* aed = (const int*)d_in[3];
    const int* ost = (const int*)d_in[4];
    const int* oed = (const int*)d_in[5];
    const int* sid = (const int*)d_in[6];
    const float* E    = (const float*)d_in[7];
    const float* Wtp  = (const float*)d_in[8];
    const float* btp  = (const float*)d_in[9];
    const float* Wat  = (const float*)d_in[10];
    const float* bat  = (const float*)d_in[11];
    const float* Wg   = (const float*)d_in[12];
    const float* bg   = (const float*)d_in[13];
    const float* g0   = (const float*)d_in[14];
    const float* b0   = (const float*)d_in[15];
    const float* W1   = (const float*)d_in[16];
    const float* bl1  = (const float*)d_in[17];
    const float* g1   = (const float*)d_in[18];
    const float* b1   = (const float*)d_in[19];
    const float* Wc   = (const float*)d_in[20];
    const float* bc   = (const float*)d_in[21];
    const float* Wc1  = (const float*)d_in[22];
    const float* bc1  = (const float*)d_in[23];
    float* outp = (float*)d_out;

    float* fw = (float*)d_ws;
    float* emb = fw;                                   // 786432
    float* nf  = fw + 786432;                          // 49152 -> 835584
    int*   hasin = (int*)(fw + 835584);                // 64
    float* hasedge = fw + 835648;                      // 4 (pad to 835712)
    float* xv  = fw + 835712;                          // 100352 -> 936064
    float* agg = fw + 936064;                          // 98304  -> 1034368
    float* raw = fw + 1034368;                         // 49152  -> 1083520
    float* abm = fw + 1083520;                         // 524288 -> 1607808
    unsigned short* w1t = (unsigned short*)(fw + 1607808); // 393216 us -> fl 1804416
    unsigned short* wfg = (unsigned short*)(fw + 1804416); // 4608 us

    k_pre<<<1473, 256, 0, stream>>>(emb_in, g0, b0, emb, W1, w1t,
                                    Wc, Wc1, g1, b1, wfg,
                                    ast, aed, ost, oed, sid, xv, nf);
    dim3 gs1(24, 2, 7);
    k_skinny<<<gs1, 256, 0, stream>>>(xv, Wtp, btp, nf, 1568, 1539, 224);
    k_graph<<<4, 256, 0, stream>>>(nf, ast, aed, ost, oed, E, Wat, bat, hasin, hasedge, agg, raw);
    k_skinny<<<gs1, 256, 0, stream>>>(agg, Wg, bg, raw, 1536, 1536, 224);
    k_scatter<<<64, 256, 0, stream>>>(raw, nf, hasin, hasedge, ast, ost, emb);
    k_gemm<<<512, 64, 0, stream>>>(emb, w1t, abm);
    dim3 g6(16, 16, 4);
    k_hidden3<<<g6, 256, 0, stream>>>(abm, bl1, masks, wfg, bc, bc1, outp);
}

// Round 11
// 225.938 us; speedup vs baseline: 1.3375x; 1.0507x over previous
//
#include <hip/hip_runtime.h>

// ---------------- helpers ----------------
__device__ __forceinline__ unsigned short f2bf(float f) {
    union { float f; unsigned u; } v; v.f = f;
    unsigned u = v.u;
    unsigned r = (u + 0x7fffu + ((u >> 16) & 1u)) >> 16;
    return (unsigned short)r;
}
__device__ __forceinline__ float bfup(int x) {
    union { unsigned u; float f; } v; v.u = ((unsigned)(unsigned short)x) << 16; return v.f;
}

typedef __attribute__((ext_vector_type(8))) short short8;
typedef __attribute__((ext_vector_type(4))) float floatx4;

// dims
#define Bn 4
#define Ln 256
#define Hn 768
#define Tn 16
#define PITCH 288   // bf16 pitch: 144 dwords, 144%32=16 -> 2-way (free) LDS aliasing

// ---------------- K1: LN (0..1023) + W1t (1024..1407) + Wf table (1408) + spans (1409..1472)
__global__ __launch_bounds__(256) void k_pre(const float* __restrict__ x,
                                             const float* __restrict__ g,
                                             const float* __restrict__ be,
                                             float* __restrict__ out,
                                             const float* __restrict__ W1,
                                             unsigned short* __restrict__ w1t,
                                             const float* __restrict__ Wc,
                                             const float* __restrict__ Wc1,
                                             const float* __restrict__ g1,
                                             const float* __restrict__ b1,
                                             unsigned short* __restrict__ wfg,
                                             const int* __restrict__ ast_, const int* __restrict__ aed_,
                                             const int* __restrict__ ost_, const int* __restrict__ oed_,
                                             const int* __restrict__ sid_,
                                             float* __restrict__ xv,
                                             float* __restrict__ nf) {
    int bid = blockIdx.x, tid = threadIdx.x;
    if (bid < 1024) {
        int row = bid;
        const float* xr = x + (size_t)row * Hn;
        float v0 = xr[tid], v1 = xr[tid + 256], v2 = xr[tid + 512];
        float s = v0 + v1 + v2;
        float q = v0 * v0 + v1 * v1 + v2 * v2;
        __shared__ float sm[4], qm[4];
        for (int o = 32; o > 0; o >>= 1) { s += __shfl_down(s, o); q += __shfl_down(q, o); }
        if ((tid & 63) == 0) { sm[tid >> 6] = s; qm[tid >> 6] = q; }
        __syncthreads();
        float S = sm[0] + sm[1] + sm[2] + sm[3];
        float Q = qm[0] + qm[1] + qm[2] + qm[3];
        float mean = S * (1.f / 768.f);
        float rstd = rsqrtf(Q * (1.f / 768.f) - mean * mean + 1e-5f);
        float* o0 = out + (size_t)row * Hn;
        o0[tid]       = (v0 - mean) * rstd * g[tid]       + be[tid];
        o0[tid + 256] = (v1 - mean) * rstd * g[tid + 256] + be[tid + 256];
        o0[tid + 512] = (v2 - mean) * rstd * g[tid + 512] + be[tid + 512];
    } else if (bid < 1408) {
        __shared__ float tile[32][33];
        int idx = bid - 1024;
        int kt = idx % 24, nt = idx / 24;
        int k0 = kt * 32, n0 = nt * 32;
        int rowoff = (n0 < 256) ? 0 : 768;
        int col0 = n0 & 255;
        int r = tid >> 3, c = (tid & 7) * 4;
        float4 v = *(const float4*)(W1 + (size_t)(rowoff + k0 + r) * 256 + col0 + c);
        tile[r][c] = v.x; tile[r][c + 1] = v.y; tile[r][c + 2] = v.z; tile[r][c + 3] = v.w;
        __syncthreads();
        ushort4 o;
        o.x = f2bf(tile[c][r]); o.y = f2bf(tile[c + 1][r]);
        o.z = f2bf(tile[c + 2][r]); o.w = f2bf(tile[c + 3][r]);
        *(ushort4*)(w1t + (size_t)(n0 + r) * 768 + k0 + c) = o;
    } else if (bid == 1408) {
        // Wf table + bf16 gamma/beta
#pragma unroll
        for (int u = 0; u < 2; ++u) {
            int e = tid + u * 256;
            int s = e >> 6, l = e & 63;
            int qq2 = l >> 4, nn2 = l & 15;
            short8 wv;
#pragma unroll
            for (int t = 0; t < 8; ++t) {
                int k = s * 32 + qq2 * 8 + t;
                float v = (nn2 < 6) ? Wc[k * 6 + nn2] : ((nn2 < 8) ? Wc1[k * 2 + (nn2 - 6)] : 0.f);
                wv[t] = (short)f2bf(v);
            }
            *(short8*)(wfg + e * 8) = wv;
        }
        wfg[4096 + tid] = f2bf(g1[tid]);
        wfg[4352 + tid] = f2bf(b1[tid]);
    } else {
        // spans with own LN stats (reads pristine emb_in = x)
        __shared__ float rstdA[3], rstdO[3], cc[2];
        __shared__ float sred[4], qred[4];
        int n = bid - 1409, b = n >> 4;
        int ast = ast_[n], aed = aed_[n], ost = ost_[n], oed = oed_[n], sid = sid_[n];
        int na = aed - ast + 1, no2 = oed - ost + 1;
        if (tid == 0) { cc[0] = 0.f; cc[1] = 0.f; }
        __syncthreads();
        for (int slot = 0; slot < 6; ++slot) {
            int isA = slot < 3;
            int off = isA ? slot : slot - 3;
            int cnt = isA ? na : no2;
            int row = (isA ? ast : ost) + off;
            if (off < cnt) {
                const float* xr = x + (size_t)(b * 256 + row) * Hn;
                float v0 = xr[tid], v1 = xr[tid + 256], v2 = xr[tid + 512];
                float s = v0 + v1 + v2;
                float q = v0 * v0 + v1 * v1 + v2 * v2;
                for (int o = 32; o > 0; o >>= 1) { s += __shfl_down(s, o); q += __shfl_down(q, o); }
                if ((tid & 63) == 0) { sred[tid >> 6] = s; qred[tid >> 6] = q; }
            }
            __syncthreads();
            if (off < cnt && tid == 0) {
                float S = sred[0] + sred[1] + sred[2] + sred[3];
                float Q = qred[0] + qred[1] + qred[2] + qred[3];
                float mean = S * (1.f / 768.f);
                float rstd = rsqrtf(Q * (1.f / 768.f) - mean * mean + 1e-5f);
                if (isA) { rstdA[off] = rstd; cc[0] += mean * rstd; }
                else     { rstdO[off] = rstd; cc[1] += mean * rstd; }
            }
            __syncthreads();
        }
        float ai = 1.f / (float)na, oi = 1.f / (float)no2;
        float cA = cc[0] * ai, cO = cc[1] * oi;
        float* xrr = xv + (size_t)n * 1568;
        const float* eb = x + (size_t)b * Ln * Hn;
        for (int r = tid; r < 1568; r += 256) {
            float v;
            if (r < 768) {
                float sa = 0.f;
                for (int l = 0; l < na; ++l) sa = fmaf(eb[(ast + l) * Hn + r], rstdA[l], sa);
                v = fmaf(g[r], sa * ai - cA, be[r]);
            } else if (r < 1536) {
                int h = r - 768;
                float so = 0.f;
                for (int l = 0; l < no2; ++l) so = fmaf(eb[(ost + l) * Hn + h], rstdO[l], so);
                v = fmaf(g[h], so * oi - cO, be[h]);
            } else if (r < 1539) {
                v = (sid - 2 == r - 1536) ? 1.f : 0.f;
            } else {
                v = 0.f;
            }
            xrr[r] = v;
        }
        float* nr = nf + (size_t)n * Hn;
        nr[tid] = 0.f; nr[tid + 256] = 0.f; nr[tid + 512] = 0.f;
    }
}

// ---------------- split-K skinny GEMM: C[M x 768] += A[M x Kpad] @ B[Kb x 768]
__global__ __launch_bounds__(256) void k_skinny(const float* __restrict__ A,
                                                const float* __restrict__ B,
                                                const float* __restrict__ bias,
                                                float* __restrict__ C,
                                                int Kpad, int Kb, int Kc) {
    __shared__ float At[32][33], Bt[32][33];
    int tid = threadIdx.x;
    int n0 = blockIdx.x * 32, m0 = blockIdx.y * 32, z = blockIdx.z;
    int kbeg = z * Kc;
    int kend = kbeg + Kc; if (kend > Kpad) kend = Kpad;
    int lr = tid >> 3, lc = (tid & 7) * 4;
    int tm = tid >> 3, tn4 = (tid & 7) * 4;
    float acc0 = 0.f, acc1 = 0.f, acc2 = 0.f, acc3 = 0.f;
    for (int k0 = kbeg; k0 < kend; k0 += 32) {
        float4 av = *(const float4*)(A + (size_t)(m0 + lr) * Kpad + k0 + lc);
        At[lr][lc] = av.x; At[lr][lc + 1] = av.y; At[lr][lc + 2] = av.z; At[lr][lc + 3] = av.w;
        int gk = k0 + lr;
        float4 bv = {0.f, 0.f, 0.f, 0.f};
        if (gk < Kb) bv = *(const float4*)(B + (size_t)gk * 768 + n0 + lc);
        Bt[lr][lc] = bv.x; Bt[lr][lc + 1] = bv.y; Bt[lr][lc + 2] = bv.z; Bt[lr][lc + 3] = bv.w;
        __syncthreads();
#pragma unroll
        for (int k = 0; k < 32; ++k) {
            float a = At[tm][k];
            acc0 = fmaf(a, Bt[k][tn4], acc0);
            acc1 = fmaf(a, Bt[k][tn4 + 1], acc1);
            acc2 = fmaf(a, Bt[k][tn4 + 2], acc2);
            acc3 = fmaf(a, Bt[k][tn4 + 3], acc3);
        }
        __syncthreads();
    }
    if (z == 0) {
        acc0 += bias[n0 + tn4];
        acc1 += bias[n0 + tn4 + 1];
        acc2 += bias[n0 + tn4 + 2];
        acc3 += bias[n0 + tn4 + 3];
    }
    float* dst = C + (size_t)(m0 + tm) * 768 + n0 + tn4;
    atomicAdd(&dst[0], acc0);
    atomicAdd(&dst[1], acc1);
    atomicAdd(&dst[2], acc2);
    atomicAdd(&dst[3], acc3);
}

// ---------------- K4: graph attention + aggregation (LDS-staged) ----------------
__global__ __launch_bounds__(256) void k_graph(const float* __restrict__ nf,
                                               const int* __restrict__ ast_, const int* __restrict__ aed_,
                                               const int* __restrict__ ost_, const int* __restrict__ oed_,
                                               const float* __restrict__ E,
                                               const float* __restrict__ Wat,
                                               const float* __restrict__ bat,
                                               int* __restrict__ hasin, float* __restrict__ hasedge,
                                               float* __restrict__ agg, float* __restrict__ raw) {
    int b = blockIdx.x, tid = threadIdx.x;
    __shared__ float nfs[16][780];
    __shared__ float Es[2][768];
    __shared__ int ast[16], aed[16], ost[16], oed[16];
    __shared__ float red[256];
    __shared__ float nrm[16], p[16], q[16], rr[2];
    __shared__ float ws2[16][16];
    __shared__ float aes[16][2];
    __shared__ unsigned m0b[16], m1b[16];
    const float* nfb = nf + (size_t)b * 16 * Hn;
    for (int e = tid; e < 3072; e += 256) {
        int r = e / 192, c = (e - r * 192) * 4;
        float4 v = *(const float4*)(nfb + r * Hn + c);
        nfs[r][c] = v.x; nfs[r][c + 1] = v.y; nfs[r][c + 2] = v.z; nfs[r][c + 3] = v.w;
    }
    for (int e = tid; e < 1536; e += 256) ((float*)Es)[e] = E[e];
    if (tid < 16) {
        int n = b * 16 + tid;
        ast[tid] = ast_[n]; aed[tid] = aed_[n]; ost[tid] = ost_[n]; oed[tid] = oed_[n];
        m0b[tid] = 0u; m1b[tid] = 0u;
    }
    __syncthreads();
    int t = tid >> 4, lane = tid & 15;
    float ss = 0.f, pp = 0.f, qq = 0.f;
    for (int h = lane; h < 768; h += 16) {
        float v = nfs[t][h];
        ss = fmaf(v, v, ss);
        float lr = v > 0.f ? v : 0.2f * v;
        pp = fmaf(lr, Wat[h], pp);
        qq = fmaf(lr, Wat[768 + h], qq);
    }
    red[tid] = ss; __syncthreads();
    if (tid < 16) { float s = 0.f; for (int k2 = 0; k2 < 16; ++k2) s += red[tid * 16 + k2]; nrm[tid] = sqrtf(s); }
    __syncthreads();
    red[tid] = pp; __syncthreads();
    if (tid < 16) { float s = 0.f; for (int k2 = 0; k2 < 16; ++k2) s += red[tid * 16 + k2]; p[tid] = s; }
    __syncthreads();
    red[tid] = qq; __syncthreads();
    if (tid < 16) { float s = 0.f; for (int k2 = 0; k2 < 16; ++k2) s += red[tid * 16 + k2]; q[tid] = s; }
    __syncthreads();
    float rp = 0.f;
    if (tid < 32) {
        int e = tid >> 4;
        for (int h = lane; h < 768; h += 16) {
            float v = Es[e][h];
            float lr = v > 0.f ? v : 0.2f * v;
            rp = fmaf(lr, Wat[1536 + h], rp);
        }
    }
    red[tid] = rp; __syncthreads();
    if (tid < 2) { float s = 0.f; for (int k2 = 0; k2 < 16; ++k2) s += red[tid * 16 + k2]; rr[tid] = s; }
    __syncthreads();
    {
        int i = tid >> 4, j = tid & 15;
        const float4* ri = (const float4*)nfs[i];
        const float4* rj = (const float4*)nfs[j];
        float dot = 0.f;
#pragma unroll 4
        for (int h4 = 0; h4 < 192; ++h4) {
            float4 a = ri[h4], c = rj[h4];
            dot = fmaf(a.x, c.x, dot); dot = fmaf(a.y, c.y, dot);
            dot = fmaf(a.z, c.z, dot); dot = fmaf(a.w, c.w, dot);
        }
        float sim = dot / (fmaxf(nrm[i], 1e-8f) * fmaxf(nrm[j], 1e-8f));
        bool ok = (sim > 0.f) && (i != j);
        if (ok && ast[i] == ast[j] && aed[i] == aed[j]) atomicOr(&m0b[i], 1u << j);
        if (ok && ost[i] == ost[j] && oed[i] == oed[j]) atomicOr(&m1b[i], 1u << j);
    }
    __syncthreads();
    if (tid < 16) {
        int tt = tid;
        float battn = bat[0];
        float sc[32];
        float mx = -3.4e38f;
        bool hi = false;
#pragma unroll
        for (int s = 0; s < 16; ++s) {
            bool e0 = (m0b[s] >> tt) & 1u;   // emask[t,s,0] = m0[s,t]
            bool e1 = (m1b[s] >> tt) & 1u;
            float base = p[tt] + q[s] + battn;
            float v0 = e0 ? (base + rr[0]) : -1e9f;
            float v1 = e1 ? (base + rr[1]) : -1e9f;
            sc[2 * s] = v0; sc[2 * s + 1] = v1;
            mx = fmaxf(mx, fmaxf(v0, v1));
            hi = hi || e0 || e1;
        }
        float sum = 0.f;
#pragma unroll
        for (int k2 = 0; k2 < 32; ++k2) { float e = expf(sc[k2] - mx); sc[k2] = e; sum += e; }
        float inv = 1.f / sum;
        float ae0 = 0.f, ae1 = 0.f;
#pragma unroll
        for (int s = 0; s < 16; ++s) {
            float w0 = sc[2 * s] * inv, w1 = sc[2 * s + 1] * inv;
            ws2[tt][s] = w0 + w1;
            ae0 += w0; ae1 += w1;
        }
        aes[tt][0] = ae0; aes[tt][1] = ae1;
        hasin[b * 16 + tt] = hi ? 1 : 0;
        red[tid] = hi ? 1.f : 0.f;
    }
    __syncthreads();
    if (tid == 0) {
        float he = 0.f;
        for (int k2 = 0; k2 < 16; ++k2) he = fmaxf(he, red[k2]);
        hasedge[b] = he;
    }
    for (int nn = 0; nn < 16; ++nn) {
        int n = b * 16 + nn;
        float ae0 = aes[nn][0], ae1 = aes[nn][1];
        float* ag = agg + (size_t)n * 1536;
        float* rw = raw + (size_t)n * Hn;
        for (int f = tid; f < 768; f += 256) {
            float s = 0.f;
#pragma unroll
            for (int s16 = 0; s16 < 16; ++s16) s = fmaf(ws2[nn][s16], nfs[s16][f], s);
            ag[f] = s;
            ag[768 + f] = ae0 * Es[0][f] + ae1 * Es[1][f];
            rw[f] = 0.f;
        }
    }
}

// ---------------- K5b: select + scatter-add into emb ----------------
__global__ __launch_bounds__(256) void k_scatter(const float* __restrict__ raw,
                                                 const float* __restrict__ nf,
                                                 const int* __restrict__ hasin, const float* __restrict__ hasedge,
                                                 const int* __restrict__ ast_, const int* __restrict__ ost_,
                                                 float* __restrict__ emb) {
    int n = blockIdx.x, b = n >> 4, tid = threadIdx.x;
    if (hasedge[b] == 0.f) return;
    int center = (ast_[n] + ost_[n]) >> 1;
    float* dst = emb + (size_t)(b * Ln + center) * Hn;
    int hi = hasin[n];
    const float* src = hi ? (raw + (size_t)n * Hn) : (nf + (size_t)n * Hn);
    for (int h = tid; h < 768; h += 256) {
        float v = src[h];
        if (hi) v = fmaxf(v, 0.f);
        atomicAdd(&dst[h], v);
    }
}

// ---------------- K7: MFMA GEMM  abm[1024][512] = bf16(emb) @ w1t^T (inline cvt)
__global__ __launch_bounds__(64) void k_gemm(const float* __restrict__ emb,
                                             const unsigned short* __restrict__ w1t,
                                             float* __restrict__ abm) {
    int wid = blockIdx.x;                 // 512 waves
    int m0 = (wid >> 4) * 32;
    int n0 = (wid & 15) * 32;
    int lane = threadIdx.x;
    int r = lane & 15, g = lane >> 4;
    const float* Af0 = emb + (size_t)(m0 + r) * 768 + g * 8;
    const float* Af1 = emb + (size_t)(m0 + 16 + r) * 768 + g * 8;
    const short8* Bp0 = (const short8*)(w1t + (size_t)(n0 + r) * 768 + g * 8);
    const short8* Bp1 = (const short8*)(w1t + (size_t)(n0 + 16 + r) * 768 + g * 8);
    floatx4 acc00 = {0.f, 0.f, 0.f, 0.f}, acc01 = {0.f, 0.f, 0.f, 0.f};
    floatx4 acc10 = {0.f, 0.f, 0.f, 0.f}, acc11 = {0.f, 0.f, 0.f, 0.f};
#pragma unroll 4
    for (int ks = 0; ks < 768; ks += 32) {
        float4 x0 = *(const float4*)(Af0 + ks);
        float4 x1 = *(const float4*)(Af0 + ks + 4);
        float4 y0 = *(const float4*)(Af1 + ks);
        float4 y1 = *(const float4*)(Af1 + ks + 4);
        short8 a0, a1;
        union { float f; unsigned u; } cv;
#define PK(dst, idx, val) { cv.f = (val); dst[idx] = (short)((cv.u + 0x8000u) >> 16); }
        PK(a0, 0, x0.x) PK(a0, 1, x0.y) PK(a0, 2, x0.z) PK(a0, 3, x0.w)
        PK(a0, 4, x1.x) PK(a0, 5, x1.y) PK(a0, 6, x1.z) PK(a0, 7, x1.w)
        PK(a1, 0, y0.x) PK(a1, 1, y0.y) PK(a1, 2, y0.z) PK(a1, 3, y0.w)
        PK(a1, 4, y1.x) PK(a1, 5, y1.y) PK(a1, 6, y1.z) PK(a1, 7, y1.w)
#undef PK
        short8 b0 = Bp0[ks >> 3];
        short8 b1 = Bp1[ks >> 3];
        acc00 = __builtin_amdgcn_mfma_f32_16x16x32_bf16(a0, b0, acc00, 0, 0, 0);
        acc01 = __builtin_amdgcn_mfma_f32_16x16x32_bf16(a0, b1, acc01, 0, 0, 0);
        acc10 = __builtin_amdgcn_mfma_f32_16x16x32_bf16(a1, b0, acc10, 0, 0, 0);
        acc11 = __builtin_amdgcn_mfma_f32_16x16x32_bf16(a1, b1, acc11, 0, 0, 0);
    }
#pragma unroll
    for (int t = 0; t < 4; ++t) {
        int row = g * 4 + t;
        abm[(size_t)(m0 + row) * 512 + n0 + r]           = acc00[t];
        abm[(size_t)(m0 + row) * 512 + n0 + 16 + r]      = acc01[t];
        abm[(size_t)(m0 + 16 + row) * 512 + n0 + r]      = acc10[t];
        abm[(size_t)(m0 + 16 + row) * 512 + n0 + 16 + r] = acc11[t];
    }
}

// ---------------- K11: fully fused LN-stats + GELU + MFMA-proj ----------------
__global__ __launch_bounds__(256) void k_hidden3(const float* __restrict__ abm,
                                                 const float* __restrict__ bl1,
                                                 const float* __restrict__ masks,
                                                 const unsigned short* __restrict__ wfg,
                                                 const float* __restrict__ bc,
                                                 const float* __restrict__ bc1,
                                                 float* __restrict__ out) {
    __shared__ unsigned short As[16][PITCH];
    __shared__ unsigned short Bs[16][PITCH];
    __shared__ unsigned short gsh[256], bsh[256];
    __shared__ short8 Wf[8][64];
    __shared__ float Ds[16][16];
    __shared__ float ms[16][16];
    __shared__ float sAs[16], qAs[16], sBs[16], qBs[16];
    int tid = threadIdx.x;
    int jt = blockIdx.x, it = blockIdx.y, b = blockIdx.z;
    int rowA = b * 256 + it * 16;
    int rowB = b * 256 + jt * 16;
    // staging: thread (r=tid>>4, sg=tid&15) handles 16 k's; stats reduced via shuffles
    {
        int r = tid >> 4, sg = tid & 15;
        const float* Ar = abm + (size_t)(rowA + r) * 512 + sg * 16;
        const float* Br = abm + (size_t)(rowB + r) * 512 + 256 + sg * 16;
        const float* Lr = bl1 + sg * 16;
        float sa = 0.f, qa = 0.f, sb = 0.f, qb = 0.f;
        short8 va0, va1, vb0, vb1;
#pragma unroll
        for (int u = 0; u < 4; ++u) {
            float4 av = *(const float4*)(Ar + u * 4);
            float4 bv = *(const float4*)(Br + u * 4);
            float4 lv = *(const float4*)(Lr + u * 4);
            float aa[4] = {av.x, av.y, av.z, av.w};
            float bb[4] = {bv.x + lv.x, bv.y + lv.y, bv.z + lv.z, bv.w + lv.w};
#pragma unroll
            for (int e = 0; e < 4; ++e) {
                unsigned short ah = f2bf(aa[e]), bh = f2bf(bb[e]);
                float af = bfup(ah), bf2 = bfup(bh);
                sa += af; qa = fmaf(af, af, qa);
                sb += bf2; qb = fmaf(bf2, bf2, qb);
                int pos = u * 4 + e;
                if (pos < 8) { va0[pos] = (short)ah; vb0[pos] = (short)bh; }
                else         { va1[pos - 8] = (short)ah; vb1[pos - 8] = (short)bh; }
            }
        }
        *(short8*)&As[r][sg * 16]     = va0;
        *(short8*)&As[r][sg * 16 + 8] = va1;
        *(short8*)&Bs[r][sg * 16]     = vb0;
        *(short8*)&Bs[r][sg * 16 + 8] = vb1;
        // 16-lane shuffle reduction (groups are contiguous within the wave)
        for (int o = 8; o > 0; o >>= 1) {
            sa += __shfl_down(sa, o); qa += __shfl_down(qa, o);
            sb += __shfl_down(sb, o); qb += __shfl_down(qb, o);
        }
        if (sg == 0) { sAs[r] = sa; qAs[r] = qa; sBs[r] = sb; qBs[r] = qb; }
    }
    // staged table loads (built once by k_pre)
#pragma unroll
    for (int u = 0; u < 2; ++u) {
        int e = tid + u * 256;
        ((short8*)Wf)[e] = *(const short8*)(wfg + e * 8);
    }
    gsh[tid] = wfg[4096 + tid];
    bsh[tid] = wfg[4352 + tid];
    {
        int di = tid >> 4, dj = tid & 15;
        ms[di][dj] = masks[((size_t)(b * 256 + it * 16 + di)) * 256 + jt * 16 + dj];
    }
    __syncthreads();
    // wave 0: D tile via 8 MFMAs from staged bf16
    if (tid < 64) {
        int m = tid & 15, q = tid >> 4;
        floatx4 acc = {0.f, 0.f, 0.f, 0.f};
#pragma unroll
        for (int s = 0; s < 8; ++s) {
            short8 a8 = *(const short8*)&As[m][s * 32 + q * 8];
            short8 b8 = *(const short8*)&Bs[m][s * 32 + q * 8];
            acc = __builtin_amdgcn_mfma_f32_16x16x32_bf16(a8, b8, acc, 0, 0, 0);
        }
#pragma unroll
        for (int rg = 0; rg < 4; ++rg) Ds[q * 4 + rg][m] = acc[rg];
    }
    __syncthreads();

    int lane = tid & 63, w = tid >> 6;
    int m = lane & 15, q = lane >> 4;
    int iA = w * 4 + (m & 3);
    int jB0 = m >> 2;
    int n = m;
    float bcs_l = (n < 6) ? bc[n] : ((n < 8) ? bc1[n - 6] : 0.f);
    const float inv256 = 1.f / 256.f;
    const float K1 = -1.5957691216f, K2 = -0.0713548163f;

    // per-p LN constants
    float rr4[4], cc4[4];
#pragma unroll
    for (int p = 0; p < 4; ++p) {
        int jB = p * 4 + jB0;
        float mu = (sAs[iA] + sBs[jB]) * inv256;
        float E2 = (qAs[iA] + 2.f * Ds[iA][jB] + qBs[jB]) * inv256;
        float r_ = rsqrtf(E2 - mu * mu + 1e-5f);
        rr4[p] = r_;
        cc4[p] = -mu * r_;
    }
    floatx4 acc0 = {0.f, 0.f, 0.f, 0.f};
    floatx4 acc1 = {0.f, 0.f, 0.f, 0.f};
    floatx4 acc2 = {0.f, 0.f, 0.f, 0.f};
    floatx4 acc3 = {0.f, 0.f, 0.f, 0.f};

#pragma unroll 2
    for (int s = 0; s < 8; ++s) {
        int ko = s * 32 + q * 8;
        short8 a8 = *(const short8*)&As[iA][ko];
        short8 g8 = *(const short8*)&gsh[ko];
        short8 v8 = *(const short8*)&bsh[ko];
        short8 wv = Wf[s][lane];
        float af[8], gf[8], vf[8];
#pragma unroll
        for (int t = 0; t < 8; ++t) { af[t] = bfup(a8[t]); gf[t] = bfup(g8[t]); vf[t] = bfup(v8[t]); }
#define PSTEP(P, ACC) do {                                                        \
        short8 b8 = *(const short8*)&Bs[P * 4 + jB0][ko];                         \
        float r_ = rr4[P], c_ = cc4[P];                                           \
        short8 yv;                                                                \
        _Pragma("unroll")                                                         \
        for (int t = 0; t < 8; ++t) {                                             \
            float x = fmaf(af[t] + bfup(b8[t]), r_, c_);                          \
            x = fmaf(x, gf[t], vf[t]);                                            \
            float mm = fmaf(x * x, K2, K1);                                       \
            float e = __expf(x * mm);                                             \
            float y = x * __builtin_amdgcn_rcpf(1.f + e);                         \
            union { float f; unsigned u; } cv; cv.f = y;                          \
            yv[t] = (short)((cv.u + 0x8000u) >> 16);                              \
        }                                                                         \
        ACC = __builtin_amdgcn_mfma_f32_16x16x32_bf16(yv, wv, ACC, 0, 0, 0);      \
    } while (0)
        PSTEP(0, acc0);
        PSTEP(1, acc1);
        PSTEP(2, acc2);
        PSTEP(3, acc3);
#undef PSTEP
    }

    if (n < 8) {
#pragma unroll
        for (int rg = 0; rg < 4; ++rg) {
            int mp = q * 4 + rg;
            int il = w * 4 + (mp & 3);
            int base_j = mp >> 2;
            size_t rowbase = ((size_t)(b * 256 + it * 16 + il)) * 256 + jt * 16;
            {
                int jl = 0 * 4 + base_j;
                out[(rowbase + jl) * 8 + n] = (acc0[rg] + bcs_l) * ms[il][jl];
            }
            {
                int jl = 1 * 4 + base_j;
                out[(rowbase + jl) * 8 + n] = (acc1[rg] + bcs_l) * ms[il][jl];
            }
            {
                int jl = 2 * 4 + base_j;
                out[(rowbase + jl) * 8 + n] = (acc2[rg] + bcs_l) * ms[il][jl];
            }
            {
                int jl = 3 * 4 + base_j;
                out[(rowbase + jl) * 8 + n] = (acc3[rg] + bcs_l) * ms[il][jl];
            }
        }
    }
}

// ---------------- launch ----------------
extern "C" void kernel_launch(void* const* d_in, const int* in_sizes, int n_in,
                              void* d_out, int out_size, void* d_ws, size_t ws_size,
                              hipStream_t stream) {
    (void)in_sizes; (void)n_in; (void)out_size; (void)ws_size;
    const float* emb_in = (const float*)d_in[0];
    const float* masks  = (const float*)d_in[1];
    const int* ast = (const int*)d_in[2];
    const int* aed = (const int*)d_in[3];
    const int* ost = (const int*)d_in[4];
    const int* oed = (const int*)d_in[5];
    const int* sid = (const int*)d_in[6];
    const float* E    = (const float*)d_in[7];
    const float* Wtp  = (const float*)d_in[8];
    const float* btp  = (const float*)d_in[9];
    const float* Wat  = (const float*)d_in[10];
    const float* bat  = (const float*)d_in[11];
    const float* Wg   = (const float*)d_in[12];
    const float* bg   = (const float*)d_in[13];
    const float* g0   = (const float*)d_in[14];
    const float* b0   = (const float*)d_in[15];
    const float* W1   = (const float*)d_in[16];
    const float* bl1  = (const float*)d_in[17];
    const float* g1   = (const float*)d_in[18];
    const float* b1   = (const float*)d_in[19];
    const float* Wc   = (const float*)d_in[20];
    const float* bc   = (const float*)d_in[21];
    const float* Wc1  = (const float*)d_in[22];
    const float* bc1  = (const float*)d_in[23];
    float* outp = (float*)d_out;

    float* fw = (float*)d_ws;
    float* emb = fw;                                   // 786432
    float* nf  = fw + 786432;                          // 49152 -> 835584
    int*   hasin = (int*)(fw + 835584);                // 64
    float* hasedge = fw + 835648;                      // 4 (pad to 835712)
    float* xv  = fw + 835712;                          // 100352 -> 936064
    float* agg = fw + 936064;                          // 98304  -> 1034368
    float* raw = fw + 1034368;                         // 49152  -> 1083520
    float* abm = fw + 1083520;                         // 524288 -> 1607808
    unsigned short* w1t = (unsigned short*)(fw + 1607808); // 393216 us -> fl 1804416
    unsigned short* wfg = (unsigned short*)(fw + 1804416); // 4608 us

    k_pre<<<1473, 256, 0, stream>>>(emb_in, g0, b0, emb, W1, w1t,
                                    Wc, Wc1, g1, b1, wfg,
                                    ast, aed, ost, oed, sid, xv, nf);
    dim3 gs1(24, 2, 7);
    k_skinny<<<gs1, 256, 0, stream>>>(xv, Wtp, btp, nf, 1568, 1539, 224);
    k_graph<<<4, 256, 0, stream>>>(nf, ast, aed, ost, oed, E, Wat, bat, hasin, hasedge, agg, raw);
    k_skinny<<<gs1, 256, 0, stream>>>(agg, Wg, bg, raw, 1536, 1536, 224);
    k_scatter<<<64, 256, 0, stream>>>(raw, nf, hasin, hasedge, ast, ost, emb);
    k_gemm<<<512, 64, 0, stream>>>(emb, w1t, abm);
    dim3 g6(16, 16, 4);
    k_hidden3<<<g6, 256, 0, stream>>>(abm, bl1, masks, wfg, bc, bc1, outp);
}